// Round 7
// baseline (512.233 us; speedup 1.0000x reference)
//
#include <hip/hip_runtime.h>
#include <hip/hip_bf16.h>

// ---------------------------------------------------------------------------
// PCELayer R12: conv_mfma v9 — trade accumulator size for occupancy.
// R10 audit: conv is LDS-latency bound (per-window wall ~15k cy vs 3.4k ideal)
// with only 2 waves/SIMD (acc=128 AGPR caps at 8 waves/CU; R9 proved (256,3)
// can't override). v9: block = 2 output rows, wave tile 64co x 64w ->
// acc = 2x2xf32x16 = 64 AGPR, ~148 regs/wave -> 12 waves/CU (3 blocks x 4).
// LDS 16.5K xls + 24K wls (single buf) = 41.5K -> 3 blocks fit. Reads/MFMA
// rises 0.75->1.0 (LDS floor 69->77us) but 3 waves/SIMD + 3 desynced blocks
// cover the ds_read latency that dominated. setprio(1) around MFMA (T5).
// Non-conv stack kept at R11 (combine-vec, GN2 fused in pw2, stats inlined).
// Workspace (153.6 MB): head 16K | wp1T 128K | wp2T 128K | XT 16.8M (->ccl)
//   | WT 2.4M | YS 134.2M (-> h1cl 67M | h2cl 16.8M | h3 8.4M)
// ---------------------------------------------------------------------------

#define B_ 16
#define CIN_ 128
#define COUT_ 128
#define H_ 64
#define W_ 64
#define HW_ 4096
#define E_ 8
#define FF_ 8
#define GC_ 32
#define HID_ 64
#define HC_ 512

typedef __hip_bfloat16 bf16;
typedef __bf16 bf16x8 __attribute__((ext_vector_type(8)));
typedef float f32x4 __attribute__((ext_vector_type(4)));
typedef float f32x16 __attribute__((ext_vector_type(16)));

__device__ __forceinline__ float siluf(float v) { return v / (1.f + __expf(-v)); }
__device__ __forceinline__ float bf2f(bf16 v) { return __bfloat162float(v); }
__device__ __forceinline__ bf16 f2bf(float v) { return __float2bfloat16(v); }

// async 16B/lane global->LDS copy. lds must be the wave-uniform segment base;
// HW writes lane i at lds + i*16. g is the per-lane global address.
__device__ __forceinline__ void async16(void* lds, const void* g) {
  __builtin_amdgcn_global_load_lds(
      (const __attribute__((address_space(1))) unsigned int*)g,
      (__attribute__((address_space(3))) unsigned int*)lds, 16, 0, 0);
}

// ---------------- router gate ----------------------------------------------
__global__ void gate_kernel(const float* __restrict__ w1, const float* __restrict__ b1,
                            const float* __restrict__ w2, const float* __restrict__ b2,
                            float* __restrict__ wts) {
  int p = threadIdx.x;
  if (p >= 16) return;
  int i = p >> 2, j = p & 3;
  float cy = (i + 0.5f) * 0.25f;
  float cx = (j + 0.5f) * 0.25f;
  float feats[GC_];
#pragma unroll
  for (int f = 0; f < FF_; ++f) {
    float fr = 3.14159265358979f * (float)(1 << f);
    float ay = cy * fr, ax = cx * fr;
    feats[f] = sinf(ay);
    feats[FF_ + f] = cosf(ay);
    feats[2 * FF_ + f] = sinf(ax);
    feats[3 * FF_ + f] = cosf(ax);
  }
  float hid[HID_];
  for (int k = 0; k < HID_; ++k) {
    float a = b1[k];
#pragma unroll
    for (int m = 0; m < GC_; ++m) a = fmaf(feats[m], w1[m * HID_ + k], a);
    hid[k] = siluf(a);
  }
  float lg[E_];
  float mx = -1e30f;
#pragma unroll
  for (int e = 0; e < E_; ++e) {
    float a = b2[e];
    for (int k = 0; k < HID_; ++k) a = fmaf(hid[k], w2[k * E_ + e], a);
    lg[e] = a;
    mx = fmaxf(mx, a);
  }
  float s = 0.f;
#pragma unroll
  for (int e = 0; e < E_; ++e) { lg[e] = __expf(lg[e] - mx); s += lg[e]; }
  float inv = 1.f / s;
#pragma unroll
  for (int e = 0; e < E_; ++e) wts[p * E_ + e] = lg[e] * inv;
}

// ---------------- x -> channels-last bf16 ----------------------------------
__global__ __launch_bounds__(256) void xt_kernel(const float* __restrict__ x,
                                                 bf16* __restrict__ xT) {
  __shared__ float t[128][65];
  int b = blockIdx.x >> 6, h = blockIdx.x & 63;
  int tid = threadIdx.x;
  int w = tid & 63, c4 = tid >> 6;
  const float* xb = x + ((size_t)(b * 128) * 64 + h) * 64;
#pragma unroll 4
  for (int rep = 0; rep < 32; ++rep) {
    int ci = rep * 4 + c4;
    t[ci][w] = xb[(size_t)ci * HW_ + w];
  }
  __syncthreads();
  bf16* dst = xT + (size_t)(b * 64 + h) * 8192;
#pragma unroll 4
  for (int rep = 0; rep < 32; ++rep) {
    int o = rep * 256 + tid;
    int cg = o >> 9, w2 = (o >> 3) & 63, lo = o & 7;
    dst[o] = f2bf(t[cg * 8 + lo][w2]);
  }
}

// ---------------- w_exp -> wT bf16 -----------------------------------------
__global__ void wt_kernel(const float* __restrict__ w_exp, bf16* __restrict__ wT) {
  int idx = blockIdx.x * 256 + threadIdx.x;
  if (idx >= 1179648) return;
  int lo = idx & 7;
  int co = (idx >> 3) & 127;
  int cg = (idx >> 10) & 15;
  int rest = idx >> 14;
  int tap = rest % 9, e = rest / 9;
  int ci = cg * 8 + lo;
  wT[idx] = f2bf(w_exp[(((size_t)(e * 128 + co) * 128 + ci) * 9) + tap]);
}

// ---------------- pw weights fp32 -> bf16 ----------------------------------
__global__ void wpT_kernel(const float* __restrict__ w_pw1, const float* __restrict__ w_pw2,
                           bf16* __restrict__ wp1T, bf16* __restrict__ wp2T) {
  int idx = blockIdx.x * 256 + threadIdx.x;
  if (idx < 65536) wp1T[idx] = f2bf(w_pw1[idx]);
  else if (idx < 131072) wp2T[idx - 65536] = f2bf(w_pw2[idx - 65536]);
}

// ---------------- expert conv via MFMA (v9: 64-reg acc, 12 waves/CU) -------
// grid: 4096 = e(8) x b(16) x rp(32 row-pairs), XCD-swizzled on b.
// block: 4 waves; wave (wm = wave>>1 co-half, wr = wave&1 row) computes
// 64 co x 64 w for output row h0+wr. acc = 2x2 x f32x16 = 64 AGPR.
__global__ __launch_bounds__(256, 3) void conv_mfma(
    const bf16* __restrict__ xT, const bf16* __restrict__ wT,
    float* __restrict__ statsE, bf16* __restrict__ ys) {
  __shared__ __align__(16) char xls[4 * 4224];   // [cg4][r4][slot66]x16B = 16.5K
  __shared__ __align__(16) char wls[3 * 8192];   // [ts3][cg4][co128]x16B = 24K
  __shared__ float red[4][4][2];

  int blk = blockIdx.x;
  // XCD swizzle: xcd = blk&7 -> b = xcd*2 + bsub. Bijective over 4096 blocks.
  int xcd = blk & 7;
  int r2 = blk >> 3;
  int b = xcd * 2 + (r2 & 1);
  int rest = r2 >> 1;                 // 0..255
  int rp = rest & 31, e = rest >> 5;

  int tid = threadIdx.x, lane = tid & 63, wave = tid >> 6;
  int hi = lane >> 5, l31 = lane & 31;
  int wr = wave & 1, wm = wave >> 1;
  int h0 = rp * 2;

  // ---- one-time zeroing: edge slots (0,65) all (cg,r); invalid halo rows --
  if (tid < 32) {
    int cg = tid >> 3, rem = tid & 7;
    int r = rem >> 1, edge = rem & 1;
    *(uint4*)(xls + cg * 4224 + r * 1056 + edge * 1040) = make_uint4(0u, 0u, 0u, 0u);
  }
  int rbad = (rp == 0) ? 0 : (rp == 31 ? 3 : -1);
  if (rbad >= 0) {
#pragma unroll
    for (int i = 0; i < 2; ++i) {
      int idx = tid + 256 * i;
      if (idx < 264) {
        int cg = idx / 66, slot = idx - cg * 66;
        *(uint4*)(xls + cg * 4224 + rbad * 1056 + slot * 16) = make_uint4(0u, 0u, 0u, 0u);
      }
    }
  }

  f32x16 acc[2][2];
#pragma unroll
  for (int mt = 0; mt < 2; ++mt)
#pragma unroll
    for (int nt = 0; nt < 2; ++nt)
#pragma unroll
      for (int r = 0; r < 16; ++r) acc[mt][nt][r] = 0.f;

  for (int q = 0; q < 4; ++q) {
    if (q) __syncthreads();  // all waves done reading xls/wls from last quarter
    // ---- stage x quarter: wave = cg stages its 4 rows (valid only) -------
    {
      int cg = wave;
#pragma unroll
      for (int r = 0; r < 4; ++r) {
        int h = h0 - 1 + r;
        if ((unsigned)h < 64u) {
          const char* g = (const char*)xT +
              ((size_t)((b * 64 + h) * 16) + q * 4 + cg) * 1024 + lane * 16;
          async16(xls + cg * 4224 + r * 1056 + 16, g);
        }
      }
    }
    // ---- stage weights for dr=0 (taps 0..2 of this quarter) --------------
#pragma unroll
    for (int s = 0; s < 6; ++s) {
      int seg = wave * 6 + s;            // ts(3) x cg(4) x cb(2)
      int ts = seg >> 3, rem = seg & 7;
      int cg = rem >> 1, cb = rem & 1;
      const char* g = (const char*)wT +
          ((size_t)(((e * 9 + ts) * 16) + q * 4 + cg) * 128 + cb * 64) * 16 + lane * 16;
      async16(wls + (ts * 4 + cg) * 2048 + cb * 1024, g);
    }
    __syncthreads();  // drains vmcnt(0): x quarter + dr0 weights ready

    for (int dr = 0; dr < 3; ++dr) {
      int r_local = wr + dr;
      __builtin_amdgcn_s_setprio(1);
#pragma unroll
      for (int ds = 0; ds < 3; ++ds) {
#pragma unroll
        for (int ks = 0; ks < 2; ++ks) {
          int cgl = ks * 2 + hi;
          bf16x8 af[2], bfr[2];
#pragma unroll
          for (int mt = 0; mt < 2; ++mt)
            af[mt] = *(const bf16x8*)(wls + (ds * 4 + cgl) * 2048 +
                                      (wm * 64 + mt * 32 + l31) * 16);
#pragma unroll
          for (int nt = 0; nt < 2; ++nt)
            bfr[nt] = *(const bf16x8*)(xls + cgl * 4224 + r_local * 1056 +
                                       (nt * 32 + l31 + ds) * 16);
#pragma unroll
          for (int mt = 0; mt < 2; ++mt)
#pragma unroll
            for (int nt = 0; nt < 2; ++nt)
              acc[mt][nt] = __builtin_amdgcn_mfma_f32_32x32x16_bf16(
                  af[mt], bfr[nt], acc[mt][nt], 0, 0, 0);
        }
      }
      __builtin_amdgcn_s_setprio(0);
      if (dr < 2) {
        __syncthreads();  // everyone done reading wls for this dr group
        // stage next dr group's 3 taps into the (single) buffer
#pragma unroll
        for (int s = 0; s < 6; ++s) {
          int seg = wave * 6 + s;
          int ts = seg >> 3, rem = seg & 7;
          int cg = rem >> 1, cb = rem & 1;
          const char* g = (const char*)wT +
              ((size_t)(((e * 9 + (dr + 1) * 3 + ts) * 16) + q * 4 + cg) * 128 + cb * 64) * 16 +
              lane * 16;
          async16(wls + (ts * 4 + cg) * 2048 + cb * 1024, g);
        }
        __syncthreads();  // staged (drains vmcnt)
      }
    }
  }

  // ---- epilogue: C/D 32x32: col=lane&31 (w), row=(r&3)+8*(r>>2)+4*hi (co) -
  int hh = h0 + wr;
  bf16* yb = ys + (size_t)((e * 16 + b) * 128) * 4096;
#pragma unroll
  for (int mt = 0; mt < 2; ++mt) {
    float s0 = 0.f, ss0 = 0.f, s1 = 0.f, ss1 = 0.f;
#pragma unroll
    for (int nt = 0; nt < 2; ++nt) {
      int w = nt * 32 + l31;
      int pos = hh * 64 + w;
#pragma unroll
      for (int r = 0; r < 16; ++r) {
        float v = acc[mt][nt][r];
        if (r < 8) { s0 += v; ss0 += v * v; } else { s1 += v; ss1 += v * v; }
        int row = (r & 3) + 8 * (r >> 2) + 4 * hi;
        yb[(size_t)(wm * 64 + mt * 32 + row) * 4096 + pos] = f2bf(v);
      }
    }
#pragma unroll
    for (int off = 32; off; off >>= 1) {
      s0 += __shfl_down(s0, off, 64);
      ss0 += __shfl_down(ss0, off, 64);
      s1 += __shfl_down(s1, off, 64);
      ss1 += __shfl_down(ss1, off, 64);
    }
    if (lane == 0) {
      red[wave][mt * 2][0] = s0; red[wave][mt * 2][1] = ss0;
      red[wave][mt * 2 + 1][0] = s1; red[wave][mt * 2 + 1][1] = ss1;
    }
  }
  __syncthreads();
  if (tid < 16) {
    int g = tid >> 1, which = tid & 1;   // g = wm*4 + mt*2 + half
    int wmg = g >> 2, sub = g & 3;
    float t = red[wmg * 2][sub][which] + red[wmg * 2 + 1][sub][which];
    atomicAdd(&statsE[((e * 16 + b) * 8 + g) * 2 + which], t);
  }
}

// ---------------- combine -> bf16 channels-last (octet-vectorized) ---------
__global__ __launch_bounds__(256) void combine_cl(
    const float* __restrict__ x, const bf16* __restrict__ ys,
    const float* __restrict__ stE, const float* __restrict__ gns,
    const float* __restrict__ gnb, const float* __restrict__ wts,
    bf16* __restrict__ ccl) {
  __shared__ bf16 tile[64][132];
  int b = blockIdx.x >> 6, h = blockIdx.x & 63;
  int t = threadIdx.x;
  int oct = t & 7, cq = t >> 3;        // cq in 0..31; co = cq*4 + k
  int w0 = oct * 8;
  int gidx = cq >> 2;                  // co>>4 (constant over k)
  int pid = (h >> 4) * 4 + (w0 >> 4);
  int pos = h * 64 + w0;

  float m_[8], r_[8], wt_[8];
#pragma unroll
  for (int e = 0; e < 8; ++e) {
    float S = stE[((e * 16 + b) * 8 + gidx) * 2];
    float SS = stE[((e * 16 + b) * 8 + gidx) * 2 + 1];
    float mean = S * (1.f / 65536.f);
    float var = SS * (1.f / 65536.f) - mean * mean;
    m_[e] = mean;
    r_[e] = rsqrtf(var + 1e-5f);
    wt_[e] = wts[pid * 8 + e];
  }

#pragma unroll
  for (int k = 0; k < 4; ++k) {
    int co = cq * 4 + k;
    const float* xp = x + ((size_t)(b * 128 + co) << 12) + pos;
    float v[8];
    float4 xa = *(const float4*)xp;
    float4 xb2 = *(const float4*)(xp + 4);
    v[0] = xa.x; v[1] = xa.y; v[2] = xa.z; v[3] = xa.w;
    v[4] = xb2.x; v[5] = xb2.y; v[6] = xb2.z; v[7] = xb2.w;
#pragma unroll
    for (int e = 0; e < 8; ++e) {
      uint4 u = *(const uint4*)(ys + ((size_t)((e * 16 + b) * 128 + co) << 12) + pos);
      const bf16* pv = (const bf16*)&u;
      float sc = r_[e] * gns[e * 128 + co];
      float sh = gnb[e * 128 + co] - m_[e] * sc;
#pragma unroll
      for (int j = 0; j < 8; ++j) {
        float yn = bf2f(pv[j]) * sc + sh;
        v[j] = fmaf(siluf(yn), wt_[e], v[j]);
      }
    }
#pragma unroll
    for (int j = 0; j < 8; ++j) tile[w0 + j][co] = f2bf(v[j]);
  }
  __syncthreads();
  int row = t >> 2, q = t & 3;
  char* dst = (char*)ccl + ((size_t)(b * 4096 + h * 64 + row)) * 256 + q * 64;
  const char* src = (const char*)&tile[row][0] + q * 64;
#pragma unroll
  for (int i = 0; i < 4; ++i)
    *(uint4*)(dst + i * 16) = *(const uint4*)(src + i * 16);
}

// ---------------- pw1 MFMA: h1[hc=512][n=65536] = w[hc][ci] @ ccl[n][ci] ---
__global__ __launch_bounds__(256) void pw1_mfma(
    const bf16* __restrict__ ccl, const bf16* __restrict__ wp1T,
    bf16* __restrict__ h1cl, float* __restrict__ stats1) {
  __shared__ __align__(16) char ls[65536];  // als 32K | bls 32K ; reused as tile
  __shared__ float red[4][2][2];
  char* als = ls;
  char* bls = ls + 32768;
  int blk = blockIdx.x;
  int ntile = blk & 511, mtile = blk >> 9;
  int n0 = ntile * 128, m0 = mtile * 128;
  int t = threadIdx.x, lane = t & 63, wave = t >> 6;
  int quad = lane >> 4, l15 = lane & 15;
  int b = n0 >> 12;

#pragma unroll
  for (int i = 0; i < 8; ++i) {
    int id = t + 256 * i;
    int r = id >> 4, c = id & 15;
    *(uint4*)(als + c * 2048 + r * 16) =
        *(const uint4*)((const char*)wp1T + (size_t)(m0 + r) * 256 + c * 16);
    *(uint4*)(bls + c * 2048 + r * 16) =
        *(const uint4*)((const char*)ccl + (size_t)(n0 + r) * 256 + c * 16);
  }
  __syncthreads();

  f32x4 acc[8][2];
#pragma unroll
  for (int mt = 0; mt < 8; ++mt)
#pragma unroll
    for (int nt = 0; nt < 2; ++nt) acc[mt][nt] = (f32x4){0.f, 0.f, 0.f, 0.f};

#pragma unroll
  for (int kc = 0; kc < 4; ++kc) {
    int cgq = kc * 4 + quad;
    bf16x8 af[8];
#pragma unroll
    for (int mt = 0; mt < 8; ++mt)
      af[mt] = *(const bf16x8*)(als + cgq * 2048 + (mt * 16 + l15) * 16);
    bf16x8 bfr[2];
#pragma unroll
    for (int nt = 0; nt < 2; ++nt)
      bfr[nt] = *(const bf16x8*)(bls + cgq * 2048 + (wave * 32 + nt * 16 + l15) * 16);
#pragma unroll
    for (int mt = 0; mt < 8; ++mt)
#pragma unroll
      for (int nt = 0; nt < 2; ++nt)
        acc[mt][nt] = __builtin_amdgcn_mfma_f32_16x16x32_bf16(
            af[mt], bfr[nt], acc[mt][nt], 0, 0, 0);
  }

  __syncthreads();  // everyone done with als/bls
  float s[2] = {0.f, 0.f}, ss[2] = {0.f, 0.f};
  bf16* tile = (bf16*)ls;  // row stride 132 elems = 264 B
#pragma unroll
  for (int mt = 0; mt < 8; ++mt) {
    int gi = mt >> 2;
#pragma unroll
    for (int nt = 0; nt < 2; ++nt) {
      int n = wave * 32 + nt * 16 + l15;
#pragma unroll
      for (int r = 0; r < 4; ++r) {
        float v = acc[mt][nt][r];
        s[gi] += v;
        ss[gi] += v * v;
        tile[n * 132 + mt * 16 + quad * 4 + r] = f2bf(v);
      }
    }
  }
#pragma unroll
  for (int gi = 0; gi < 2; ++gi) {
#pragma unroll
    for (int off = 32; off; off >>= 1) {
      s[gi] += __shfl_down(s[gi], off, 64);
      ss[gi] += __shfl_down(ss[gi], off, 64);
    }
  }
  if (lane == 0) {
    red[wave][0][0] = s[0]; red[wave][0][1] = ss[0];
    red[wave][1][0] = s[1]; red[wave][1][1] = ss[1];
  }
  __syncthreads();
  if (t < 4) {
    int gi = t >> 1, which = t & 1;
    float v = red[0][gi][which] + red[1][gi][which] + red[2][gi][which] + red[3][gi][which];
    atomicAdd(&stats1[(b * 8 + mtile * 2 + gi) * 2 + which], v);
  }
#pragma unroll
  for (int i = 0; i < 8; ++i) {
    int id = t + 256 * i;             // 0..2047
    int r = id >> 4, q = id & 15;     // 128 rows x 16 chunks of 16B
    char* dst = (char*)h1cl + (size_t)(n0 + r) * 1024 + m0 * 2 + q * 16;
    const char* src = (const char*)tile + r * 264 + q * 16;
    *(uint4*)dst = *(const uint4*)src;
  }
}

// ---------------- dw3x3: LDS-staged GN1+SiLU tile + sliding stencil --------
// (stats1 read RAW; finalize inlined)
__global__ __launch_bounds__(256) void dw_cl(
    const bf16* __restrict__ h1cl, const float* __restrict__ w_dw,
    const float* __restrict__ st1, const float* __restrict__ gs,
    const float* __restrict__ gb, bf16* __restrict__ h2cl,
    float* __restrict__ stats2) {
  __shared__ __align__(16) bf16 tile[18 * 66 * 16];  // 38016 B
  __shared__ float red2[4][2];
  int blk = blockIdx.x;
  int ht = blk & 3, hcg = (blk >> 2) & 31, b = blk >> 7;
  int h0 = ht * 16;
  int hc0 = hcg * 16;
  int hcb = hcg >> 2;  // 64-hc GN group
  int t = threadIdx.x;

  float S1 = st1[(b * 8 + hcb) * 2], SS1 = st1[(b * 8 + hcb) * 2 + 1];
  float mean = S1 * (1.f / 262144.f);
  float var1 = SS1 * (1.f / 262144.f) - mean * mean;
  float rstd = rsqrtf(var1 + 1e-5f);
  float scale[16], shift[16];
#pragma unroll
  for (int j = 0; j < 16; ++j) {
    float g = gs[hc0 + j];
    scale[j] = rstd * g;
    shift[j] = gb[hc0 + j] - mean * rstd * g;
  }

  // ---- stage: 18 x 66 (row, wslot) pairs; wslot 0 and 65 are zero pad ----
  for (int i = 0; i < 5; ++i) {
    int idx = t + 256 * i;
    if (idx >= 1188) break;
    int row = idx / 66, wslot = idx - row * 66;
    int hh = h0 - 1 + row;
    int w = wslot - 1;
    int swz = (wslot >> 2) & 3;  // quarter swizzle base
    bf16* dst = tile + (row * 66 + wslot) * 16;
    if ((unsigned)hh < 64u && (unsigned)w < 64u) {
      const char* p = (const char*)h1cl + ((size_t)(b * 4096 + hh * 64 + w) * 512 + hc0) * 2;
      uint4 a0 = *(const uint4*)p;
      uint4 a1 = *(const uint4*)(p + 16);
      const bf16* pv = (const bf16*)&a0;
      const bf16* pv1 = (const bf16*)&a1;
      bf16 outv[16];
#pragma unroll
      for (int j = 0; j < 8; ++j)
        outv[j] = f2bf(siluf(bf2f(pv[j]) * scale[j] + shift[j]));
#pragma unroll
      for (int j = 0; j < 8; ++j)
        outv[8 + j] = f2bf(siluf(bf2f(pv1[j]) * scale[8 + j] + shift[8 + j]));
      // place logical quarter qq at physical slot (qq+swz)&3
#pragma unroll
      for (int qq = 0; qq < 4; ++qq) {
        int ph = (qq + swz) & 3;
        *(uint2*)(dst + ph * 4) = *(const uint2*)(outv + qq * 4);
      }
    } else {
      *(uint4*)dst = make_uint4(0u, 0u, 0u, 0u);
      *(uint4*)(dst + 8) = make_uint4(0u, 0u, 0u, 0u);
    }
  }
  __syncthreads();

  // ---- compute: thread = (w, quarter q of 4 hc), slide over 16 rows ----
  int w = t & 63, q = t >> 6;
  float wv[9][4];
#pragma unroll
  for (int j = 0; j < 4; ++j) {
    int hc = hc0 + q * 4 + j;
#pragma unroll
    for (int tap = 0; tap < 9; ++tap) wv[tap][j] = w_dw[hc * 9 + tap];
  }

  f32x4 win[3][3];  // [ring(row%3)][dw]
  float acc_s = 0.f, acc_ss = 0.f;

  auto ld4 = [&](int r, int dwi) -> f32x4 {
    int slot = w + dwi;
    int ph = (q + (slot >> 2)) & 3;
    const bf16* p = tile + (r * 66 + slot) * 16 + ph * 4;
    uint2 u = *(const uint2*)p;
    const bf16* pb = (const bf16*)&u;
    return (f32x4){bf2f(pb[0]), bf2f(pb[1]), bf2f(pb[2]), bf2f(pb[3])};
  };

#pragma unroll
  for (int dwi = 0; dwi < 3; ++dwi) {
    win[0][dwi] = ld4(0, dwi);
    win[1][dwi] = ld4(1, dwi);
  }
#pragma unroll
  for (int orow = 0; orow < 16; ++orow) {
    int rnew = orow + 2;
    int ringn = rnew % 3;
#pragma unroll
    for (int dwi = 0; dwi < 3; ++dwi) win[ringn][dwi] = ld4(rnew, dwi);
    f32x4 acc = (f32x4){0.f, 0.f, 0.f, 0.f};
#pragma unroll
    for (int dr = 0; dr < 3; ++dr) {
      int ring = (orow + dr) % 3;
#pragma unroll
      for (int dwi = 0; dwi < 3; ++dwi) {
#pragma unroll
        for (int j = 0; j < 4; ++j)
          acc[j] = fmaf(win[ring][dwi][j], wv[dr * 3 + dwi][j], acc[j]);
      }
    }
#pragma unroll
    for (int j = 0; j < 4; ++j) { acc_s += acc[j]; acc_ss += acc[j] * acc[j]; }
    if (!(orow & 1) && !(w & 1)) {
      int hglob = h0 + orow;
      int pos2 = (hglob >> 1) * 32 + (w >> 1);
      bf16 tmp[4];
#pragma unroll
      for (int j = 0; j < 4; ++j) tmp[j] = f2bf(acc[j]);
      *(uint2*)((char*)h2cl + ((size_t)(b * 1024 + pos2) * 512 + hc0 + q * 4) * 2) =
          *(const uint2*)tmp;
    }
  }

  // ---- stats reduction: one atomic pair per block into (b, hcb) ----
#pragma unroll
  for (int off = 32; off; off >>= 1) {
    acc_s += __shfl_down(acc_s, off, 64);
    acc_ss += __shfl_down(acc_ss, off, 64);
  }
  int wave = t >> 6;
  if ((t & 63) == 0) { red2[wave][0] = acc_s; red2[wave][1] = acc_ss; }
  __syncthreads();
  if (t < 2) {
    float v = red2[0][t] + red2[1][t] + red2[2][t] + red2[3][t];
    atomicAdd(&stats2[(b * 8 + hcb) * 2 + t], v);
  }
}

// ---------------- pw2 MFMA (GN2+SiLU fused on bls staging) -----------------
// h3[co=128][n=16384] = w[co][hc] @ silu(GN2(h2raw))[n][hc]
__global__ __launch_bounds__(256) void pw2_mfma(
    const bf16* __restrict__ h2, const bf16* __restrict__ wp2T,
    const float* __restrict__ st2, const float* __restrict__ gs2,
    const float* __restrict__ gb2, float* __restrict__ h3,
    float* __restrict__ stats3) {
  __shared__ __align__(16) char als[2][8192];
  __shared__ __align__(16) char bls[2][4096];
  __shared__ float red[4][8][2];
  int blk = blockIdx.x;
  int n0 = blk * 64;
  int b = n0 >> 10, posb = n0 & 1023;
  int t = threadIdx.x, lane = t & 63, wave = t >> 6;
  int quad = lane >> 4, l15 = lane & 15;
  int wbase = wave * 16;
  int c4 = t >> 6, r = t & 63;

  // normalize+silu h2 octet (kc,c4) for row n0+r, write 16B to dst
  auto load_bls = [&](char* dst, int kc) {
    int hc0 = (kc * 4 + c4) * 8;
    int g = hc0 >> 6;
    float S = st2[(b * 8 + g) * 2], SS = st2[(b * 8 + g) * 2 + 1];
    float mean = S * (1.f / 262144.f);
    float rstd = rsqrtf(SS * (1.f / 262144.f) - mean * mean + 1e-5f);
    uint4 u = *(const uint4*)((const char*)h2 + (size_t)(n0 + r) * 1024 +
                              (size_t)(kc * 4 + c4) * 16);
    const bf16* pv = (const bf16*)&u;
    bf16 outv[8];
#pragma unroll
    for (int j = 0; j < 8; ++j) {
      float xv = bf2f(pv[j]);
      xv = (xv - mean) * rstd * gs2[hc0 + j] + gb2[hc0 + j];
      outv[j] = f2bf(siluf(xv));
    }
    *(uint4*)dst = *(const uint4*)outv;
  };

  f32x4 acc[8];
#pragma unroll
  for (int mt = 0; mt < 8; ++mt) acc[mt] = (f32x4){0.f, 0.f, 0.f, 0.f};

  {
#pragma unroll
    for (int i = 0; i < 2; ++i) {
      int id = t + 256 * i;
      int cc = id >> 7, rr = id & 127;
      *(uint4*)(als[0] + cc * 2048 + rr * 16) =
          *(const uint4*)((const char*)wp2T + (size_t)rr * 1024 + cc * 16);
    }
    load_bls(bls[0] + c4 * 1024 + r * 16, 0);
  }
#pragma unroll
  for (int kc = 0; kc < 16; ++kc) {
    __syncthreads();
    if (kc + 1 < 16) {
      int nb = (kc + 1) & 1;
#pragma unroll
      for (int i = 0; i < 2; ++i) {
        int id = t + 256 * i;
        int cc = id >> 7, rr = id & 127;
        *(uint4*)(als[nb] + cc * 2048 + rr * 16) =
            *(const uint4*)((const char*)wp2T + (size_t)rr * 1024 + ((kc + 1) * 4 + cc) * 16);
      }
      load_bls(bls[nb] + c4 * 1024 + r * 16, kc + 1);
    }
    int buf = kc & 1;
    bf16x8 bf1 = *(const bf16x8*)(bls[buf] + quad * 1024 + (wbase + l15) * 16);
#pragma unroll
    for (int mt = 0; mt < 8; ++mt) {
      bf16x8 af = *(const bf16x8*)(als[buf] + quad * 2048 + (mt * 16 + l15) * 16);
      acc[mt] = __builtin_amdgcn_mfma_f32_16x16x32_bf16(af, bf1, acc[mt], 0, 0, 0);
    }
  }

#pragma unroll
  for (int mt = 0; mt < 8; ++mt) {
    float s = 0.f, ss = 0.f;
    int pos = posb + wbase + l15;
#pragma unroll
    for (int rr = 0; rr < 4; ++rr) {
      float v = acc[mt][rr];
      s += v;
      ss += v * v;
      int co = mt * 16 + quad * 4 + rr;
      h3[(size_t)(b * 128 + co) * 1024 + pos] = v;
    }
#pragma unroll
    for (int off = 32; off; off >>= 1) {
      s += __shfl_down(s, off, 64);
      ss += __shfl_down(ss, off, 64);
    }
    if (lane == 0) { red[wave][mt][0] = s; red[wave][mt][1] = ss; }
  }
  __syncthreads();
  if (t < 16) {
    int mt = t >> 1, which = t & 1;
    float v = red[0][mt][which] + red[1][mt][which] + red[2][mt][which] + red[3][mt][which];
    atomicAdd(&stats3[(b * 8 + mt) * 2 + which], v);
  }
}

// ---------------- final GN+SiLU -> d_out (fp32) ----------------------------
__global__ void out_kernel(const float* __restrict__ h3, const float* __restrict__ stats,
                           const float* __restrict__ gs, const float* __restrict__ gb,
                           float* __restrict__ out) {
  const int total = B_ * COUT_ * 1024;
  for (int idx = blockIdx.x * blockDim.x + threadIdx.x; idx < total; idx += gridDim.x * blockDim.x) {
    int c = (idx >> 10) & 127;
    int b = idx >> 17;
    int bg = b * 8 + (c >> 4);
    float S = stats[bg * 2], SS = stats[bg * 2 + 1];
    float mean = S * (1.f / 16384.f);
    float var = SS * (1.f / 16384.f) - mean * mean;
    float rstd = rsqrtf(var + 1e-5f);
    float v = (h3[idx] - mean) * rstd * gs[c] + gb[c];
    out[idx] = siluf(v);
  }
}

extern "C" void kernel_launch(void* const* d_in, const int* in_sizes, int n_in,
                              void* d_out, int out_size, void* d_ws, size_t ws_size,
                              hipStream_t stream) {
  const float* x = (const float*)d_in[0];
  const float* w_exp = (const float*)d_in[1];
  const float* gn_exp_s = (const float*)d_in[2];
  const float* gn_exp_b = (const float*)d_in[3];
  const float* w1 = (const float*)d_in[4];
  const float* b1 = (const float*)d_in[5];
  const float* w2 = (const float*)d_in[6];
  const float* b2 = (const float*)d_in[7];
  const float* w_pw1 = (const float*)d_in[8];
  const float* gn1_s = (const float*)d_in[9];
  const float* gn1_b = (const float*)d_in[10];
  const float* w_dw = (const float*)d_in[11];
  const float* gn2_s = (const float*)d_in[12];
  const float* gn2_b = (const float*)d_in[13];
  const float* w_pw2 = (const float*)d_in[14];
  const float* gn3_s = (const float*)d_in[15];
  const float* gn3_b = (const float*)d_in[16];

  char* ws = (char*)d_ws;
  const size_t WP1T_OFF = 16384;
  const size_t WP2T_OFF = WP1T_OFF + 131072;
  const size_t XT_OFF = WP2T_OFF + 131072;                 // 278528
  const size_t WT_OFF = XT_OFF + 16777216;                 // 17055744
  const size_t YS_OFF = WT_OFF + 2359296;                  // 19415040
  const size_t NEEDED = YS_OFF + 134217728;                // 153632768
  if (ws_size < NEEDED) return;

  float* wts = (float*)ws;
  float* stats1 = (float*)(ws + 1024);
  float* stats2 = (float*)(ws + 2048);
  float* stats3 = (float*)(ws + 3072);
  float* statsE = (float*)(ws + 4096);
  bf16* wp1T = (bf16*)(ws + WP1T_OFF);
  bf16* wp2T = (bf16*)(ws + WP2T_OFF);
  bf16* xT = (bf16*)(ws + XT_OFF);
  bf16* ccl = (bf16*)(ws + XT_OFF);
  bf16* wT = (bf16*)(ws + WT_OFF);
  bf16* ys = (bf16*)(ws + YS_OFF);
  bf16* h1cl = (bf16*)(ws + YS_OFF);
  bf16* h2cl = (bf16*)(ws + YS_OFF + 67108864);
  float* h3 = (float*)(ws + YS_OFF + 83886080);

  hipMemsetAsync(ws, 0, 16384, stream);
  gate_kernel<<<1, 64, 0, stream>>>(w1, b1, w2, b2, wts);
  xt_kernel<<<B_ * 64, 256, 0, stream>>>(x, xT);
  wt_kernel<<<4608, 256, 0, stream>>>(w_exp, wT);
  wpT_kernel<<<512, 256, 0, stream>>>(w_pw1, w_pw2, wp1T, wp2T);
  conv_mfma<<<4096, 256, 0, stream>>>(xT, wT, statsE, ys);
  combine_cl<<<B_ * 64, 256, 0, stream>>>(x, ys, statsE, gn_exp_s, gn_exp_b, wts, ccl);
  pw1_mfma<<<4 * 512, 256, 0, stream>>>(ccl, wp1T, h1cl, stats1);
  dw_cl<<<B_ * 32 * 4, 256, 0, stream>>>(h1cl, w_dw, stats1, gn1_s, gn1_b, h2cl, stats2);
  pw2_mfma<<<256, 256, 0, stream>>>(h2cl, wp2T, stats2, gn2_s, gn2_b, h3, stats3);
  out_kernel<<<1024, 256, 0, stream>>>(h3, stats3, gn3_s, gn3_b, (float*)d_out);
}

// Round 8
// 438.622 us; speedup vs baseline: 1.1678x; 1.1678x over previous
//
#include <hip/hip_runtime.h>
#include <hip/hip_bf16.h>

// ---------------------------------------------------------------------------
// PCELayer R13: conv_mfma reverted to R10 exactly (149.5us pareto point —
// R9/R12 occupancy experiments both lost). New change: siluf now uses
// v_rcp_f32 (__builtin_amdgcn_rcpf) instead of precise f32 division, which
// without fast-math compiles to the ~10-instruction div_scale/div_fmas/
// div_fixup sequence. ~590M SiLU evals across combine(536M)/dw(39M)/
// pw2(8.4M)/out(2.1M) were paying ~9 extra VALU ops each (~40-60us).
// rcp is ~1ulp; outputs stored as bf16 -> numerically invisible.
// Non-conv structure kept at R11 (combine-vec, GN2 fused in pw2, stats
// finalize inlined).
// Workspace (153.6 MB): head 16K | wp1T 128K | wp2T 128K | XT 16.8M (->ccl)
//   | WT 2.4M | YS 134.2M (-> h1cl 67M | h2cl 16.8M | h3 8.4M)
// ---------------------------------------------------------------------------

#define B_ 16
#define CIN_ 128
#define COUT_ 128
#define H_ 64
#define W_ 64
#define HW_ 4096
#define E_ 8
#define FF_ 8
#define GC_ 32
#define HID_ 64
#define HC_ 512

typedef __hip_bfloat16 bf16;
typedef __bf16 bf16x8 __attribute__((ext_vector_type(8)));
typedef float f32x4 __attribute__((ext_vector_type(4)));
typedef float f32x16 __attribute__((ext_vector_type(16)));

__device__ __forceinline__ float siluf(float v) {
  // v * sigmoid(v) with 1-instruction v_rcp_f32 (precise div is ~10 instrs)
  return v * __builtin_amdgcn_rcpf(1.f + __expf(-v));
}
__device__ __forceinline__ float bf2f(bf16 v) { return __bfloat162float(v); }
__device__ __forceinline__ bf16 f2bf(float v) { return __float2bfloat16(v); }

// async 16B/lane global->LDS copy. lds must be the wave-uniform segment base;
// HW writes lane i at lds + i*16. g is the per-lane global address.
__device__ __forceinline__ void async16(void* lds, const void* g) {
  __builtin_amdgcn_global_load_lds(
      (const __attribute__((address_space(1))) unsigned int*)g,
      (__attribute__((address_space(3))) unsigned int*)lds, 16, 0, 0);
}

// ---------------- router gate ----------------------------------------------
__global__ void gate_kernel(const float* __restrict__ w1, const float* __restrict__ b1,
                            const float* __restrict__ w2, const float* __restrict__ b2,
                            float* __restrict__ wts) {
  int p = threadIdx.x;
  if (p >= 16) return;
  int i = p >> 2, j = p & 3;
  float cy = (i + 0.5f) * 0.25f;
  float cx = (j + 0.5f) * 0.25f;
  float feats[GC_];
#pragma unroll
  for (int f = 0; f < FF_; ++f) {
    float fr = 3.14159265358979f * (float)(1 << f);
    float ay = cy * fr, ax = cx * fr;
    feats[f] = sinf(ay);
    feats[FF_ + f] = cosf(ay);
    feats[2 * FF_ + f] = sinf(ax);
    feats[3 * FF_ + f] = cosf(ax);
  }
  float hid[HID_];
  for (int k = 0; k < HID_; ++k) {
    float a = b1[k];
#pragma unroll
    for (int m = 0; m < GC_; ++m) a = fmaf(feats[m], w1[m * HID_ + k], a);
    hid[k] = siluf(a);
  }
  float lg[E_];
  float mx = -1e30f;
#pragma unroll
  for (int e = 0; e < E_; ++e) {
    float a = b2[e];
    for (int k = 0; k < HID_; ++k) a = fmaf(hid[k], w2[k * E_ + e], a);
    lg[e] = a;
    mx = fmaxf(mx, a);
  }
  float s = 0.f;
#pragma unroll
  for (int e = 0; e < E_; ++e) { lg[e] = __expf(lg[e] - mx); s += lg[e]; }
  float inv = 1.f / s;
#pragma unroll
  for (int e = 0; e < E_; ++e) wts[p * E_ + e] = lg[e] * inv;
}

// ---------------- x -> channels-last bf16 ----------------------------------
__global__ __launch_bounds__(256) void xt_kernel(const float* __restrict__ x,
                                                 bf16* __restrict__ xT) {
  __shared__ float t[128][65];
  int b = blockIdx.x >> 6, h = blockIdx.x & 63;
  int tid = threadIdx.x;
  int w = tid & 63, c4 = tid >> 6;
  const float* xb = x + ((size_t)(b * 128) * 64 + h) * 64;
#pragma unroll 4
  for (int rep = 0; rep < 32; ++rep) {
    int ci = rep * 4 + c4;
    t[ci][w] = xb[(size_t)ci * HW_ + w];
  }
  __syncthreads();
  bf16* dst = xT + (size_t)(b * 64 + h) * 8192;
#pragma unroll 4
  for (int rep = 0; rep < 32; ++rep) {
    int o = rep * 256 + tid;
    int cg = o >> 9, w2 = (o >> 3) & 63, lo = o & 7;
    dst[o] = f2bf(t[cg * 8 + lo][w2]);
  }
}

// ---------------- w_exp -> wT bf16 -----------------------------------------
__global__ void wt_kernel(const float* __restrict__ w_exp, bf16* __restrict__ wT) {
  int idx = blockIdx.x * 256 + threadIdx.x;
  if (idx >= 1179648) return;
  int lo = idx & 7;
  int co = (idx >> 3) & 127;
  int cg = (idx >> 10) & 15;
  int rest = idx >> 14;
  int tap = rest % 9, e = rest / 9;
  int ci = cg * 8 + lo;
  wT[idx] = f2bf(w_exp[(((size_t)(e * 128 + co) * 128 + ci) * 9) + tap]);
}

// ---------------- pw weights fp32 -> bf16 ----------------------------------
__global__ void wpT_kernel(const float* __restrict__ w_pw1, const float* __restrict__ w_pw2,
                           bf16* __restrict__ wp1T, bf16* __restrict__ wp2T) {
  int idx = blockIdx.x * 256 + threadIdx.x;
  if (idx < 65536) wp1T[idx] = f2bf(w_pw1[idx]);
  else if (idx < 131072) wp2T[idx - 65536] = f2bf(w_pw2[idx - 65536]);
}

// ---------------- expert conv via MFMA (R10 v7: 12-step SW pipeline) -------
__global__ __launch_bounds__(256, 2) void conv_mfma(
    const bf16* __restrict__ xT, const bf16* __restrict__ wT,
    float* __restrict__ statsE, bf16* __restrict__ ys) {
  __shared__ __align__(16) char xls[4 * 6336];     // [cg4][r6][slot66]x16B, padded
  __shared__ __align__(16) char wls[2][3 * 8192];  // dbuf [tap3][cg4][co128]x16B
  __shared__ float red[4][8][2];

  int blk = blockIdx.x;
  // XCD swizzle: xcd = blk&7 -> b = xcd*2 + bsub. Bijective over 2048 blocks.
  int xcd = blk & 7;
  int r2 = blk >> 3;
  int b = xcd * 2 + (r2 & 1);
  int rest = r2 >> 1;
  int rt = rest & 15, e = rest >> 4;

  int tid = threadIdx.x, lane = tid & 63, wave = tid >> 6;
  int hi = lane >> 5, l31 = lane & 31;
  int h0 = rt * 4;

  // ---- one-time zeroing: edge slots (0,65) of all rows; invalid halo rows -
  if (tid < 48) {
    int cg = tid / 12, rem = tid % 12;
    int r = rem >> 1, edge = rem & 1;
    *(uint4*)(xls + cg * 6336 + r * 1056 + edge * 1040) = make_uint4(0u, 0u, 0u, 0u);
  }
  int rbad = (rt == 0) ? 0 : (rt == 15 ? 5 : -1);
  if (rbad >= 0) {
    int cg = tid >> 6, slot = (tid & 63) + 1;
    *(uint4*)(xls + cg * 6336 + rbad * 1056 + slot * 16) = make_uint4(0u, 0u, 0u, 0u);
  }

  f32x16 acc[4][2];
#pragma unroll
  for (int mt = 0; mt < 4; ++mt)
#pragma unroll
    for (int nt = 0; nt < 2; ++nt)
#pragma unroll
      for (int r = 0; r < 16; ++r) acc[mt][nt][r] = 0.f;

  for (int q = 0; q < 4; ++q) {
    if (q) __syncthreads();  // all waves done reading xls/wls[0] last quarter
    // ---- stage x quarter: wave handles cg=wave, valid rows (slots 1..64) --
    {
      int cg = wave;
#pragma unroll
      for (int r = 0; r < 6; ++r) {
        int h = h0 - 1 + r;
        if ((unsigned)h < 64u) {
          const char* g = (const char*)xT +
              ((size_t)((b * 64 + h) * 16) + q * 4 + cg) * 1024 + lane * 16;
          async16(xls + cg * 6336 + r * 1056 + 16, g);
        }
      }
    }
    // ---- stage weights for dr=0 (taps 0..2 of this quarter) -> buf0 ------
#pragma unroll
    for (int s = 0; s < 6; ++s) {
      int seg = wave * 6 + s;            // tap(3) x cg(4) x cb(2)
      int tap = seg >> 3, rem = seg & 7;
      int cg = rem >> 1, cb = rem & 1;
      const char* g = (const char*)wT +
          ((size_t)(((e * 9 + tap) * 16) + q * 4 + cg) * 128 + cb * 64) * 16 + lane * 16;
      async16(wls[0] + (tap * 4 + cg) * 2048 + cb * 1024, g);
    }
    __syncthreads();  // drains vmcnt(0): x quarter + dr0 weights ready

    for (int dr = 0; dr < 3; ++dr) {
      int buf = dr & 1;
      if (dr < 2) {
        // prefetch next dr group's 3 taps into the other buffer; landing
        // guaranteed by the barrier at the end of this window.
#pragma unroll
        for (int s = 0; s < 6; ++s) {
          int seg = wave * 6 + s;
          int tap = seg >> 3, rem = seg & 7;
          int cg = rem >> 1, cb = rem & 1;
          const char* g = (const char*)wT +
              ((size_t)(((e * 9 + (dr + 1) * 3 + tap) * 16) + q * 4 + cg) * 128 + cb * 64) * 16 +
              lane * 16;
          async16(wls[buf ^ 1] + (tap * 4 + cg) * 2048 + cb * 1024, g);
        }
      }
      int r_local = wave + dr;
      const char* wb = wls[buf];
      const char* xrow = xls;  // + cgl*6336 + r_local*1056
      // ---- 12-step pipelined compute: step = (ds, ks, mthalf) ------------
      bf16x8 afp[2][2], bfp[2][2];
      {  // prologue: step 0 = (ds0, ks0, mh0)
        int cgl = hi;
        afp[0][0] = *(const bf16x8*)(wb + cgl * 2048 + (0 * 32 + l31) * 16);
        afp[0][1] = *(const bf16x8*)(wb + cgl * 2048 + (1 * 32 + l31) * 16);
        const char* xr = xrow + cgl * 6336 + r_local * 1056;
        bfp[0][0] = *(const bf16x8*)(xr + (0 * 32 + l31 + 0) * 16);
        bfp[0][1] = *(const bf16x8*)(xr + (1 * 32 + l31 + 0) * 16);
      }
#pragma unroll
      for (int s = 0; s < 12; ++s) {
        int mh = s & 1;
        int cura = s & 1, curb = (s >> 1) & 1;
        if (s < 11) {  // prefetch step s+1 into the other banks
          int s1 = s + 1;
          int ds1 = s1 >> 2, ks1 = (s1 >> 1) & 1, mh1 = s1 & 1;
          int cgl1 = ks1 * 2 + hi;
          const char* wt1 = wb + ds1 * 8192 + cgl1 * 2048;
          afp[s1 & 1][0] = *(const bf16x8*)(wt1 + ((mh1 * 2 + 0) * 32 + l31) * 16);
          afp[s1 & 1][1] = *(const bf16x8*)(wt1 + ((mh1 * 2 + 1) * 32 + l31) * 16);
          if (mh1 == 0) {
            const char* xr1 = xrow + cgl1 * 6336 + r_local * 1056;
            bfp[(s1 >> 1) & 1][0] = *(const bf16x8*)(xr1 + (0 * 32 + l31 + ds1) * 16);
            bfp[(s1 >> 1) & 1][1] = *(const bf16x8*)(xr1 + (1 * 32 + l31 + ds1) * 16);
          }
        }
#pragma unroll
        for (int i = 0; i < 2; ++i)
#pragma unroll
          for (int nt = 0; nt < 2; ++nt)
            acc[mh * 2 + i][nt] = __builtin_amdgcn_mfma_f32_32x32x16_bf16(
                afp[cura][i], bfp[curb][nt], acc[mh * 2 + i][nt], 0, 0, 0);
      }
      if (dr < 2) __syncthreads();  // next wls buf landed; safe to rewrite other
    }
  }

  // ---- epilogue: C/D 32x32 layout: col=lane&31, row=(r&3)+8*(r>>2)+4*hi --
  int hh = h0 + wave;
  bf16* yb = ys + (size_t)((e * 16 + b) * 128) * 4096;
#pragma unroll
  for (int mt = 0; mt < 4; ++mt) {
    float s0 = 0.f, ss0 = 0.f, s1 = 0.f, ss1 = 0.f;
#pragma unroll
    for (int nt = 0; nt < 2; ++nt) {
      int w = nt * 32 + l31;
      int pos = hh * 64 + w;
#pragma unroll
      for (int r = 0; r < 16; ++r) {
        float v = acc[mt][nt][r];
        if (r < 8) { s0 += v; ss0 += v * v; } else { s1 += v; ss1 += v * v; }
        int row = (r & 3) + 8 * (r >> 2) + 4 * hi;
        yb[(size_t)(mt * 32 + row) * 4096 + pos] = f2bf(v);
      }
    }
#pragma unroll
    for (int off = 32; off; off >>= 1) {
      s0 += __shfl_down(s0, off, 64);
      ss0 += __shfl_down(ss0, off, 64);
      s1 += __shfl_down(s1, off, 64);
      ss1 += __shfl_down(ss1, off, 64);
    }
    if (lane == 0) {
      red[wave][mt * 2][0] = s0; red[wave][mt * 2][1] = ss0;
      red[wave][mt * 2 + 1][0] = s1; red[wave][mt * 2 + 1][1] = ss1;
    }
  }
  __syncthreads();
  if (tid < 16) {
    int g = tid >> 1, which = tid & 1;
    float t = red[0][g][which] + red[1][g][which] + red[2][g][which] + red[3][g][which];
    atomicAdd(&statsE[((e * 16 + b) * 8 + g) * 2 + which], t);
  }
}

// ---------------- combine -> bf16 channels-last (octet-vectorized) ---------
__global__ __launch_bounds__(256) void combine_cl(
    const float* __restrict__ x, const bf16* __restrict__ ys,
    const float* __restrict__ stE, const float* __restrict__ gns,
    const float* __restrict__ gnb, const float* __restrict__ wts,
    bf16* __restrict__ ccl) {
  __shared__ bf16 tile[64][132];
  int b = blockIdx.x >> 6, h = blockIdx.x & 63;
  int t = threadIdx.x;
  int oct = t & 7, cq = t >> 3;        // cq in 0..31; co = cq*4 + k
  int w0 = oct * 8;
  int gidx = cq >> 2;                  // co>>4 (constant over k)
  int pid = (h >> 4) * 4 + (w0 >> 4);
  int pos = h * 64 + w0;

  float m_[8], r_[8], wt_[8];
#pragma unroll
  for (int e = 0; e < 8; ++e) {
    float S = stE[((e * 16 + b) * 8 + gidx) * 2];
    float SS = stE[((e * 16 + b) * 8 + gidx) * 2 + 1];
    float mean = S * (1.f / 65536.f);
    float var = SS * (1.f / 65536.f) - mean * mean;
    m_[e] = mean;
    r_[e] = rsqrtf(var + 1e-5f);
    wt_[e] = wts[pid * 8 + e];
  }

#pragma unroll
  for (int k = 0; k < 4; ++k) {
    int co = cq * 4 + k;
    const float* xp = x + ((size_t)(b * 128 + co) << 12) + pos;
    float v[8];
    float4 xa = *(const float4*)xp;
    float4 xb2 = *(const float4*)(xp + 4);
    v[0] = xa.x; v[1] = xa.y; v[2] = xa.z; v[3] = xa.w;
    v[4] = xb2.x; v[5] = xb2.y; v[6] = xb2.z; v[7] = xb2.w;
#pragma unroll
    for (int e = 0; e < 8; ++e) {
      uint4 u = *(const uint4*)(ys + ((size_t)((e * 16 + b) * 128 + co) << 12) + pos);
      const bf16* pv = (const bf16*)&u;
      float sc = r_[e] * gns[e * 128 + co];
      float sh = gnb[e * 128 + co] - m_[e] * sc;
#pragma unroll
      for (int j = 0; j < 8; ++j) {
        float yn = bf2f(pv[j]) * sc + sh;
        v[j] = fmaf(siluf(yn), wt_[e], v[j]);
      }
    }
#pragma unroll
    for (int j = 0; j < 8; ++j) tile[w0 + j][co] = f2bf(v[j]);
  }
  __syncthreads();
  int row = t >> 2, q = t & 3;
  char* dst = (char*)ccl + ((size_t)(b * 4096 + h * 64 + row)) * 256 + q * 64;
  const char* src = (const char*)&tile[row][0] + q * 64;
#pragma unroll
  for (int i = 0; i < 4; ++i)
    *(uint4*)(dst + i * 16) = *(const uint4*)(src + i * 16);
}

// ---------------- pw1 MFMA: h1[hc=512][n=65536] = w[hc][ci] @ ccl[n][ci] ---
__global__ __launch_bounds__(256) void pw1_mfma(
    const bf16* __restrict__ ccl, const bf16* __restrict__ wp1T,
    bf16* __restrict__ h1cl, float* __restrict__ stats1) {
  __shared__ __align__(16) char ls[65536];  // als 32K | bls 32K ; reused as tile
  __shared__ float red[4][2][2];
  char* als = ls;
  char* bls = ls + 32768;
  int blk = blockIdx.x;
  int ntile = blk & 511, mtile = blk >> 9;
  int n0 = ntile * 128, m0 = mtile * 128;
  int t = threadIdx.x, lane = t & 63, wave = t >> 6;
  int quad = lane >> 4, l15 = lane & 15;
  int b = n0 >> 12;

#pragma unroll
  for (int i = 0; i < 8; ++i) {
    int id = t + 256 * i;
    int r = id >> 4, c = id & 15;
    *(uint4*)(als + c * 2048 + r * 16) =
        *(const uint4*)((const char*)wp1T + (size_t)(m0 + r) * 256 + c * 16);
    *(uint4*)(bls + c * 2048 + r * 16) =
        *(const uint4*)((const char*)ccl + (size_t)(n0 + r) * 256 + c * 16);
  }
  __syncthreads();

  f32x4 acc[8][2];
#pragma unroll
  for (int mt = 0; mt < 8; ++mt)
#pragma unroll
    for (int nt = 0; nt < 2; ++nt) acc[mt][nt] = (f32x4){0.f, 0.f, 0.f, 0.f};

#pragma unroll
  for (int kc = 0; kc < 4; ++kc) {
    int cgq = kc * 4 + quad;
    bf16x8 af[8];
#pragma unroll
    for (int mt = 0; mt < 8; ++mt)
      af[mt] = *(const bf16x8*)(als + cgq * 2048 + (mt * 16 + l15) * 16);
    bf16x8 bfr[2];
#pragma unroll
    for (int nt = 0; nt < 2; ++nt)
      bfr[nt] = *(const bf16x8*)(bls + cgq * 2048 + (wave * 32 + nt * 16 + l15) * 16);
#pragma unroll
    for (int mt = 0; mt < 8; ++mt)
#pragma unroll
      for (int nt = 0; nt < 2; ++nt)
        acc[mt][nt] = __builtin_amdgcn_mfma_f32_16x16x32_bf16(
            af[mt], bfr[nt], acc[mt][nt], 0, 0, 0);
  }

  __syncthreads();  // everyone done with als/bls
  float s[2] = {0.f, 0.f}, ss[2] = {0.f, 0.f};
  bf16* tile = (bf16*)ls;  // row stride 132 elems = 264 B
#pragma unroll
  for (int mt = 0; mt < 8; ++mt) {
    int gi = mt >> 2;
#pragma unroll
    for (int nt = 0; nt < 2; ++nt) {
      int n = wave * 32 + nt * 16 + l15;
#pragma unroll
      for (int r = 0; r < 4; ++r) {
        float v = acc[mt][nt][r];
        s[gi] += v;
        ss[gi] += v * v;
        tile[n * 132 + mt * 16 + quad * 4 + r] = f2bf(v);
      }
    }
  }
#pragma unroll
  for (int gi = 0; gi < 2; ++gi) {
#pragma unroll
    for (int off = 32; off; off >>= 1) {
      s[gi] += __shfl_down(s[gi], off, 64);
      ss[gi] += __shfl_down(ss[gi], off, 64);
    }
  }
  if (lane == 0) {
    red[wave][0][0] = s[0]; red[wave][0][1] = ss[0];
    red[wave][1][0] = s[1]; red[wave][1][1] = ss[1];
  }
  __syncthreads();
  if (t < 4) {
    int gi = t >> 1, which = t & 1;
    float v = red[0][gi][which] + red[1][gi][which] + red[2][gi][which] + red[3][gi][which];
    atomicAdd(&stats1[(b * 8 + mtile * 2 + gi) * 2 + which], v);
  }
#pragma unroll
  for (int i = 0; i < 8; ++i) {
    int id = t + 256 * i;             // 0..2047
    int r = id >> 4, q = id & 15;     // 128 rows x 16 chunks of 16B
    char* dst = (char*)h1cl + (size_t)(n0 + r) * 1024 + m0 * 2 + q * 16;
    const char* src = (const char*)tile + r * 264 + q * 16;
    *(uint4*)dst = *(const uint4*)src;
  }
}

// ---------------- dw3x3: LDS-staged GN1+SiLU tile + sliding stencil --------
// (stats1 read RAW; finalize inlined)
__global__ __launch_bounds__(256) void dw_cl(
    const bf16* __restrict__ h1cl, const float* __restrict__ w_dw,
    const float* __restrict__ st1, const float* __restrict__ gs,
    const float* __restrict__ gb, bf16* __restrict__ h2cl,
    float* __restrict__ stats2) {
  __shared__ __align__(16) bf16 tile[18 * 66 * 16];  // 38016 B
  __shared__ float red2[4][2];
  int blk = blockIdx.x;
  int ht = blk & 3, hcg = (blk >> 2) & 31, b = blk >> 7;
  int h0 = ht * 16;
  int hc0 = hcg * 16;
  int hcb = hcg >> 2;  // 64-hc GN group
  int t = threadIdx.x;

  float S1 = st1[(b * 8 + hcb) * 2], SS1 = st1[(b * 8 + hcb) * 2 + 1];
  float mean = S1 * (1.f / 262144.f);
  float var1 = SS1 * (1.f / 262144.f) - mean * mean;
  float rstd = rsqrtf(var1 + 1e-5f);
  float scale[16], shift[16];
#pragma unroll
  for (int j = 0; j < 16; ++j) {
    float g = gs[hc0 + j];
    scale[j] = rstd * g;
    shift[j] = gb[hc0 + j] - mean * rstd * g;
  }

  // ---- stage: 18 x 66 (row, wslot) pairs; wslot 0 and 65 are zero pad ----
  for (int i = 0; i < 5; ++i) {
    int idx = t + 256 * i;
    if (idx >= 1188) break;
    int row = idx / 66, wslot = idx - row * 66;
    int hh = h0 - 1 + row;
    int w = wslot - 1;
    int swz = (wslot >> 2) & 3;  // quarter swizzle base
    bf16* dst = tile + (row * 66 + wslot) * 16;
    if ((unsigned)hh < 64u && (unsigned)w < 64u) {
      const char* p = (const char*)h1cl + ((size_t)(b * 4096 + hh * 64 + w) * 512 + hc0) * 2;
      uint4 a0 = *(const uint4*)p;
      uint4 a1 = *(const uint4*)(p + 16);
      const bf16* pv = (const bf16*)&a0;
      const bf16* pv1 = (const bf16*)&a1;
      bf16 outv[16];
#pragma unroll
      for (int j = 0; j < 8; ++j)
        outv[j] = f2bf(siluf(bf2f(pv[j]) * scale[j] + shift[j]));
#pragma unroll
      for (int j = 0; j < 8; ++j)
        outv[8 + j] = f2bf(siluf(bf2f(pv1[j]) * scale[8 + j] + shift[8 + j]));
      // place logical quarter qq at physical slot (qq+swz)&3
#pragma unroll
      for (int qq = 0; qq < 4; ++qq) {
        int ph = (qq + swz) & 3;
        *(uint2*)(dst + ph * 4) = *(const uint2*)(outv + qq * 4);
      }
    } else {
      *(uint4*)dst = make_uint4(0u, 0u, 0u, 0u);
      *(uint4*)(dst + 8) = make_uint4(0u, 0u, 0u, 0u);
    }
  }
  __syncthreads();

  // ---- compute: thread = (w, quarter q of 4 hc), slide over 16 rows ----
  int w = t & 63, q = t >> 6;
  float wv[9][4];
#pragma unroll
  for (int j = 0; j < 4; ++j) {
    int hc = hc0 + q * 4 + j;
#pragma unroll
    for (int tap = 0; tap < 9; ++tap) wv[tap][j] = w_dw[hc * 9 + tap];
  }

  f32x4 win[3][3];  // [ring(row%3)][dw]
  float acc_s = 0.f, acc_ss = 0.f;

  auto ld4 = [&](int r, int dwi) -> f32x4 {
    int slot = w + dwi;
    int ph = (q + (slot >> 2)) & 3;
    const bf16* p = tile + (r * 66 + slot) * 16 + ph * 4;
    uint2 u = *(const uint2*)p;
    const bf16* pb = (const bf16*)&u;
    return (f32x4){bf2f(pb[0]), bf2f(pb[1]), bf2f(pb[2]), bf2f(pb[3])};
  };

#pragma unroll
  for (int dwi = 0; dwi < 3; ++dwi) {
    win[0][dwi] = ld4(0, dwi);
    win[1][dwi] = ld4(1, dwi);
  }
#pragma unroll
  for (int orow = 0; orow < 16; ++orow) {
    int rnew = orow + 2;
    int ringn = rnew % 3;
#pragma unroll
    for (int dwi = 0; dwi < 3; ++dwi) win[ringn][dwi] = ld4(rnew, dwi);
    f32x4 acc = (f32x4){0.f, 0.f, 0.f, 0.f};
#pragma unroll
    for (int dr = 0; dr < 3; ++dr) {
      int ring = (orow + dr) % 3;
#pragma unroll
      for (int dwi = 0; dwi < 3; ++dwi) {
#pragma unroll
        for (int j = 0; j < 4; ++j)
          acc[j] = fmaf(win[ring][dwi][j], wv[dr * 3 + dwi][j], acc[j]);
      }
    }
#pragma unroll
    for (int j = 0; j < 4; ++j) { acc_s += acc[j]; acc_ss += acc[j] * acc[j]; }
    if (!(orow & 1) && !(w & 1)) {
      int hglob = h0 + orow;
      int pos2 = (hglob >> 1) * 32 + (w >> 1);
      bf16 tmp[4];
#pragma unroll
      for (int j = 0; j < 4; ++j) tmp[j] = f2bf(acc[j]);
      *(uint2*)((char*)h2cl + ((size_t)(b * 1024 + pos2) * 512 + hc0 + q * 4) * 2) =
          *(const uint2*)tmp;
    }
  }

  // ---- stats reduction: one atomic pair per block into (b, hcb) ----
#pragma unroll
  for (int off = 32; off; off >>= 1) {
    acc_s += __shfl_down(acc_s, off, 64);
    acc_ss += __shfl_down(acc_ss, off, 64);
  }
  int wave = t >> 6;
  if ((t & 63) == 0) { red2[wave][0] = acc_s; red2[wave][1] = acc_ss; }
  __syncthreads();
  if (t < 2) {
    float v = red2[0][t] + red2[1][t] + red2[2][t] + red2[3][t];
    atomicAdd(&stats2[(b * 8 + hcb) * 2 + t], v);
  }
}

// ---------------- pw2 MFMA (GN2+SiLU fused on bls staging) -----------------
// h3[co=128][n=16384] = w[co][hc] @ silu(GN2(h2raw))[n][hc]
__global__ __launch_bounds__(256) void pw2_mfma(
    const bf16* __restrict__ h2, const bf16* __restrict__ wp2T,
    const float* __restrict__ st2, const float* __restrict__ gs2,
    const float* __restrict__ gb2, float* __restrict__ h3,
    float* __restrict__ stats3) {
  __shared__ __align__(16) char als[2][8192];
  __shared__ __align__(16) char bls[2][4096];
  __shared__ float red[4][8][2];
  int blk = blockIdx.x;
  int n0 = blk * 64;
  int b = n0 >> 10, posb = n0 & 1023;
  int t = threadIdx.x, lane = t & 63, wave = t >> 6;
  int quad = lane >> 4, l15 = lane & 15;
  int wbase = wave * 16;
  int c4 = t >> 6, r = t & 63;

  // normalize+silu h2 octet (kc,c4) for row n0+r, write 16B to dst
  auto load_bls = [&](char* dst, int kc) {
    int hc0 = (kc * 4 + c4) * 8;
    int g = hc0 >> 6;
    float S = st2[(b * 8 + g) * 2], SS = st2[(b * 8 + g) * 2 + 1];
    float mean = S * (1.f / 262144.f);
    float rstd = rsqrtf(SS * (1.f / 262144.f) - mean * mean + 1e-5f);
    uint4 u = *(const uint4*)((const char*)h2 + (size_t)(n0 + r) * 1024 +
                              (size_t)(kc * 4 + c4) * 16);
    const bf16* pv = (const bf16*)&u;
    bf16 outv[8];
#pragma unroll
    for (int j = 0; j < 8; ++j) {
      float xv = bf2f(pv[j]);
      xv = (xv - mean) * rstd * gs2[hc0 + j] + gb2[hc0 + j];
      outv[j] = f2bf(siluf(xv));
    }
    *(uint4*)dst = *(const uint4*)outv;
  };

  f32x4 acc[8];
#pragma unroll
  for (int mt = 0; mt < 8; ++mt) acc[mt] = (f32x4){0.f, 0.f, 0.f, 0.f};

  {
#pragma unroll
    for (int i = 0; i < 2; ++i) {
      int id = t + 256 * i;
      int cc = id >> 7, rr = id & 127;
      *(uint4*)(als[0] + cc * 2048 + rr * 16) =
          *(const uint4*)((const char*)wp2T + (size_t)rr * 1024 + cc * 16);
    }
    load_bls(bls[0] + c4 * 1024 + r * 16, 0);
  }
#pragma unroll
  for (int kc = 0; kc < 16; ++kc) {
    __syncthreads();
    if (kc + 1 < 16) {
      int nb = (kc + 1) & 1;
#pragma unroll
      for (int i = 0; i < 2; ++i) {
        int id = t + 256 * i;
        int cc = id >> 7, rr = id & 127;
        *(uint4*)(als[nb] + cc * 2048 + rr * 16) =
            *(const uint4*)((const char*)wp2T + (size_t)rr * 1024 + ((kc + 1) * 4 + cc) * 16);
      }
      load_bls(bls[nb] + c4 * 1024 + r * 16, kc + 1);
    }
    int buf = kc & 1;
    bf16x8 bf1 = *(const bf16x8*)(bls[buf] + quad * 1024 + (wbase + l15) * 16);
#pragma unroll
    for (int mt = 0; mt < 8; ++mt) {
      bf16x8 af = *(const bf16x8*)(als[buf] + quad * 2048 + (mt * 16 + l15) * 16);
      acc[mt] = __builtin_amdgcn_mfma_f32_16x16x32_bf16(af, bf1, acc[mt], 0, 0, 0);
    }
  }

#pragma unroll
  for (int mt = 0; mt < 8; ++mt) {
    float s = 0.f, ss = 0.f;
    int pos = posb + wbase + l15;
#pragma unroll
    for (int rr = 0; rr < 4; ++rr) {
      float v = acc[mt][rr];
      s += v;
      ss += v * v;
      int co = mt * 16 + quad * 4 + rr;
      h3[(size_t)(b * 128 + co) * 1024 + pos] = v;
    }
#pragma unroll
    for (int off = 32; off; off >>= 1) {
      s += __shfl_down(s, off, 64);
      ss += __shfl_down(ss, off, 64);
    }
    if (lane == 0) { red[wave][mt][0] = s; red[wave][mt][1] = ss; }
  }
  __syncthreads();
  if (t < 16) {
    int mt = t >> 1, which = t & 1;
    float v = red[0][mt][which] + red[1][mt][which] + red[2][mt][which] + red[3][mt][which];
    atomicAdd(&stats3[(b * 8 + mt) * 2 + which], v);
  }
}

// ---------------- final GN+SiLU -> d_out (fp32) ----------------------------
__global__ void out_kernel(const float* __restrict__ h3, const float* __restrict__ stats,
                           const float* __restrict__ gs, const float* __restrict__ gb,
                           float* __restrict__ out) {
  const int total = B_ * COUT_ * 1024;
  for (int idx = blockIdx.x * blockDim.x + threadIdx.x; idx < total; idx += gridDim.x * blockDim.x) {
    int c = (idx >> 10) & 127;
    int b = idx >> 17;
    int bg = b * 8 + (c >> 4);
    float S = stats[bg * 2], SS = stats[bg * 2 + 1];
    float mean = S * (1.f / 16384.f);
    float var = SS * (1.f / 16384.f) - mean * mean;
    float rstd = rsqrtf(var + 1e-5f);
    float v = (h3[idx] - mean) * rstd * gs[c] + gb[c];
    out[idx] = siluf(v);
  }
}

extern "C" void kernel_launch(void* const* d_in, const int* in_sizes, int n_in,
                              void* d_out, int out_size, void* d_ws, size_t ws_size,
                              hipStream_t stream) {
  const float* x = (const float*)d_in[0];
  const float* w_exp = (const float*)d_in[1];
  const float* gn_exp_s = (const float*)d_in[2];
  const float* gn_exp_b = (const float*)d_in[3];
  const float* w1 = (const float*)d_in[4];
  const float* b1 = (const float*)d_in[5];
  const float* w2 = (const float*)d_in[6];
  const float* b2 = (const float*)d_in[7];
  const float* w_pw1 = (const float*)d_in[8];
  const float* gn1_s = (const float*)d_in[9];
  const float* gn1_b = (const float*)d_in[10];
  const float* w_dw = (const float*)d_in[11];
  const float* gn2_s = (const float*)d_in[12];
  const float* gn2_b = (const float*)d_in[13];
  const float* w_pw2 = (const float*)d_in[14];
  const float* gn3_s = (const float*)d_in[15];
  const float* gn3_b = (const float*)d_in[16];

  char* ws = (char*)d_ws;
  const size_t WP1T_OFF = 16384;
  const size_t WP2T_OFF = WP1T_OFF + 131072;
  const size_t XT_OFF = WP2T_OFF + 131072;                 // 278528
  const size_t WT_OFF = XT_OFF + 16777216;                 // 17055744
  const size_t YS_OFF = WT_OFF + 2359296;                  // 19415040
  const size_t NEEDED = YS_OFF + 134217728;                // 153632768
  if (ws_size < NEEDED) return;

  float* wts = (float*)ws;
  float* stats1 = (float*)(ws + 1024);
  float* stats2 = (float*)(ws + 2048);
  float* stats3 = (float*)(ws + 3072);
  float* statsE = (float*)(ws + 4096);
  bf16* wp1T = (bf16*)(ws + WP1T_OFF);
  bf16* wp2T = (bf16*)(ws + WP2T_OFF);
  bf16* xT = (bf16*)(ws + XT_OFF);
  bf16* ccl = (bf16*)(ws + XT_OFF);
  bf16* wT = (bf16*)(ws + WT_OFF);
  bf16* ys = (bf16*)(ws + YS_OFF);
  bf16* h1cl = (bf16*)(ws + YS_OFF);
  bf16* h2cl = (bf16*)(ws + YS_OFF + 67108864);
  float* h3 = (float*)(ws + YS_OFF + 83886080);

  hipMemsetAsync(ws, 0, 16384, stream);
  gate_kernel<<<1, 64, 0, stream>>>(w1, b1, w2, b2, wts);
  xt_kernel<<<B_ * 64, 256, 0, stream>>>(x, xT);
  wt_kernel<<<4608, 256, 0, stream>>>(w_exp, wT);
  wpT_kernel<<<512, 256, 0, stream>>>(w_pw1, w_pw2, wp1T, wp2T);
  conv_mfma<<<E_ * B_ * 16, 256, 0, stream>>>(xT, wT, statsE, ys);
  combine_cl<<<B_ * 64, 256, 0, stream>>>(x, ys, statsE, gn_exp_s, gn_exp_b, wts, ccl);
  pw1_mfma<<<4 * 512, 256, 0, stream>>>(ccl, wp1T, h1cl, stats1);
  dw_cl<<<B_ * 32 * 4, 256, 0, stream>>>(h1cl, w_dw, stats1, gn1_s, gn1_b, h2cl, stats2);
  pw2_mfma<<<256, 256, 0, stream>>>(h2cl, wp2T, stats2, gn2_s, gn2_b, h3, stats3);
  out_kernel<<<1024, 256, 0, stream>>>(h3, stats3, gn3_s, gn3_b, (float*)d_out);
}

// Round 9
// 437.616 us; speedup vs baseline: 1.1705x; 1.0023x over previous
//
#include <hip/hip_runtime.h>
#include <hip/hip_bf16.h>

// ---------------------------------------------------------------------------
// PCELayer R14 = R13 (conv at its 149.5us pareto point, rcp-SiLU) plus three
// non-conv structural cuts:
//  - pw1_mfma: grid 512 (ntile-only); ccl B-tile staged ONCE per block, mtile
//    0..3 looped internally (A from L2-hot 128KB wp1T). B-stage HBM traffic
//    67->16.8MB; 4x staging amortization. LDS 32K bls + 34K als/tile = 67.7K.
//  - prep_kernel: gate+xt+wt+wpT merged (independent) -> 3 fewer launches.
//  - out_kernel float4-vectorized; combine_cl XCD-swizzled so block for batch
//    b runs on xcd b>>1 (same L2 that conv's ys[.][b] writes went through).
// Workspace (153.6 MB): head 16K | wp1T 128K | wp2T 128K | XT 16.8M (->ccl)
//   | WT 2.4M | YS 134.2M (-> h1cl 67M | h2cl 16.8M | h3 8.4M)
// ---------------------------------------------------------------------------

#define B_ 16
#define CIN_ 128
#define COUT_ 128
#define H_ 64
#define W_ 64
#define HW_ 4096
#define E_ 8
#define FF_ 8
#define GC_ 32
#define HID_ 64
#define HC_ 512

typedef __hip_bfloat16 bf16;
typedef __bf16 bf16x8 __attribute__((ext_vector_type(8)));
typedef float f32x4 __attribute__((ext_vector_type(4)));
typedef float f32x16 __attribute__((ext_vector_type(16)));

__device__ __forceinline__ float siluf(float v) {
  // v * sigmoid(v) with 1-instruction v_rcp_f32 (precise div is ~10 instrs)
  return v * __builtin_amdgcn_rcpf(1.f + __expf(-v));
}
__device__ __forceinline__ float bf2f(bf16 v) { return __bfloat162float(v); }
__device__ __forceinline__ bf16 f2bf(float v) { return __float2bfloat16(v); }

// async 16B/lane global->LDS copy. lds must be the wave-uniform segment base;
// HW writes lane i at lds + i*16. g is the per-lane global address.
__device__ __forceinline__ void async16(void* lds, const void* g) {
  __builtin_amdgcn_global_load_lds(
      (const __attribute__((address_space(1))) unsigned int*)g,
      (__attribute__((address_space(3))) unsigned int*)lds, 16, 0, 0);
}

// ---------------- merged prep: xt | wt | wpT | gate -------------------------
// blk <1024: x->xT transpose; <5632: w_exp->wT; <6144: pw weights; ==6144: gate
__global__ __launch_bounds__(256) void prep_kernel(
    const float* __restrict__ x, bf16* __restrict__ xT,
    const float* __restrict__ w_exp, bf16* __restrict__ wT,
    const float* __restrict__ w_pw1, const float* __restrict__ w_pw2,
    bf16* __restrict__ wp1T, bf16* __restrict__ wp2T,
    const float* __restrict__ w1, const float* __restrict__ b1,
    const float* __restrict__ w2, const float* __restrict__ b2,
    float* __restrict__ wts) {
  __shared__ float t[128][65];
  int blk = blockIdx.x;
  int tid = threadIdx.x;

  if (blk < 1024) {
    // ---- xt: x -> channels-last bf16 ----
    int b = blk >> 6, h = blk & 63;
    int w = tid & 63, c4 = tid >> 6;
    const float* xb = x + ((size_t)(b * 128) * 64 + h) * 64;
#pragma unroll 4
    for (int rep = 0; rep < 32; ++rep) {
      int ci = rep * 4 + c4;
      t[ci][w] = xb[(size_t)ci * HW_ + w];
    }
    __syncthreads();
    bf16* dst = xT + (size_t)(b * 64 + h) * 8192;
#pragma unroll 4
    for (int rep = 0; rep < 32; ++rep) {
      int o = rep * 256 + tid;
      int cg = o >> 9, w2 = (o >> 3) & 63, lo = o & 7;
      dst[o] = f2bf(t[cg * 8 + lo][w2]);
    }
  } else if (blk < 5632) {
    // ---- wt: w_exp -> wT bf16 ----
    int idx = (blk - 1024) * 256 + tid;
    if (idx < 1179648) {
      int lo = idx & 7;
      int co = (idx >> 3) & 127;
      int cg = (idx >> 10) & 15;
      int rest = idx >> 14;
      int tap = rest % 9, e = rest / 9;
      int ci = cg * 8 + lo;
      wT[idx] = f2bf(w_exp[(((size_t)(e * 128 + co) * 128 + ci) * 9) + tap]);
    }
  } else if (blk < 6144) {
    // ---- wpT: pw weights fp32 -> bf16 ----
    int idx = (blk - 5632) * 256 + tid;
    if (idx < 65536) wp1T[idx] = f2bf(w_pw1[idx]);
    else wp2T[idx - 65536] = f2bf(w_pw2[idx - 65536]);
  } else {
    // ---- gate ----
    int p = tid;
    if (p >= 16) return;
    int i = p >> 2, j = p & 3;
    float cy = (i + 0.5f) * 0.25f;
    float cx = (j + 0.5f) * 0.25f;
    float feats[GC_];
#pragma unroll
    for (int f = 0; f < FF_; ++f) {
      float fr = 3.14159265358979f * (float)(1 << f);
      float ay = cy * fr, ax = cx * fr;
      feats[f] = sinf(ay);
      feats[FF_ + f] = cosf(ay);
      feats[2 * FF_ + f] = sinf(ax);
      feats[3 * FF_ + f] = cosf(ax);
    }
    float hid[HID_];
    for (int k = 0; k < HID_; ++k) {
      float a = b1[k];
#pragma unroll
      for (int m = 0; m < GC_; ++m) a = fmaf(feats[m], w1[m * HID_ + k], a);
      hid[k] = siluf(a);
    }
    float lg[E_];
    float mx = -1e30f;
#pragma unroll
    for (int e = 0; e < E_; ++e) {
      float a = b2[e];
      for (int k = 0; k < HID_; ++k) a = fmaf(hid[k], w2[k * E_ + e], a);
      lg[e] = a;
      mx = fmaxf(mx, a);
    }
    float s = 0.f;
#pragma unroll
    for (int e = 0; e < E_; ++e) { lg[e] = __expf(lg[e] - mx); s += lg[e]; }
    float inv = 1.f / s;
#pragma unroll
    for (int e = 0; e < E_; ++e) wts[p * E_ + e] = lg[e] * inv;
  }
}

// ---------------- expert conv via MFMA (R10 v7: 12-step SW pipeline) -------
__global__ __launch_bounds__(256, 2) void conv_mfma(
    const bf16* __restrict__ xT, const bf16* __restrict__ wT,
    float* __restrict__ statsE, bf16* __restrict__ ys) {
  __shared__ __align__(16) char xls[4 * 6336];     // [cg4][r6][slot66]x16B, padded
  __shared__ __align__(16) char wls[2][3 * 8192];  // dbuf [tap3][cg4][co128]x16B
  __shared__ float red[4][8][2];

  int blk = blockIdx.x;
  // XCD swizzle: xcd = blk&7 -> b = xcd*2 + bsub. Bijective over 2048 blocks.
  int xcd = blk & 7;
  int r2 = blk >> 3;
  int b = xcd * 2 + (r2 & 1);
  int rest = r2 >> 1;
  int rt = rest & 15, e = rest >> 4;

  int tid = threadIdx.x, lane = tid & 63, wave = tid >> 6;
  int hi = lane >> 5, l31 = lane & 31;
  int h0 = rt * 4;

  // ---- one-time zeroing: edge slots (0,65) of all rows; invalid halo rows -
  if (tid < 48) {
    int cg = tid / 12, rem = tid % 12;
    int r = rem >> 1, edge = rem & 1;
    *(uint4*)(xls + cg * 6336 + r * 1056 + edge * 1040) = make_uint4(0u, 0u, 0u, 0u);
  }
  int rbad = (rt == 0) ? 0 : (rt == 15 ? 5 : -1);
  if (rbad >= 0) {
    int cg = tid >> 6, slot = (tid & 63) + 1;
    *(uint4*)(xls + cg * 6336 + rbad * 1056 + slot * 16) = make_uint4(0u, 0u, 0u, 0u);
  }

  f32x16 acc[4][2];
#pragma unroll
  for (int mt = 0; mt < 4; ++mt)
#pragma unroll
    for (int nt = 0; nt < 2; ++nt)
#pragma unroll
      for (int r = 0; r < 16; ++r) acc[mt][nt][r] = 0.f;

  for (int q = 0; q < 4; ++q) {
    if (q) __syncthreads();  // all waves done reading xls/wls[0] last quarter
    // ---- stage x quarter: wave handles cg=wave, valid rows (slots 1..64) --
    {
      int cg = wave;
#pragma unroll
      for (int r = 0; r < 6; ++r) {
        int h = h0 - 1 + r;
        if ((unsigned)h < 64u) {
          const char* g = (const char*)xT +
              ((size_t)((b * 64 + h) * 16) + q * 4 + cg) * 1024 + lane * 16;
          async16(xls + cg * 6336 + r * 1056 + 16, g);
        }
      }
    }
    // ---- stage weights for dr=0 (taps 0..2 of this quarter) -> buf0 ------
#pragma unroll
    for (int s = 0; s < 6; ++s) {
      int seg = wave * 6 + s;            // tap(3) x cg(4) x cb(2)
      int tap = seg >> 3, rem = seg & 7;
      int cg = rem >> 1, cb = rem & 1;
      const char* g = (const char*)wT +
          ((size_t)(((e * 9 + tap) * 16) + q * 4 + cg) * 128 + cb * 64) * 16 + lane * 16;
      async16(wls[0] + (tap * 4 + cg) * 2048 + cb * 1024, g);
    }
    __syncthreads();  // drains vmcnt(0): x quarter + dr0 weights ready

    for (int dr = 0; dr < 3; ++dr) {
      int buf = dr & 1;
      if (dr < 2) {
        // prefetch next dr group's 3 taps into the other buffer; landing
        // guaranteed by the barrier at the end of this window.
#pragma unroll
        for (int s = 0; s < 6; ++s) {
          int seg = wave * 6 + s;
          int tap = seg >> 3, rem = seg & 7;
          int cg = rem >> 1, cb = rem & 1;
          const char* g = (const char*)wT +
              ((size_t)(((e * 9 + (dr + 1) * 3 + tap) * 16) + q * 4 + cg) * 128 + cb * 64) * 16 +
              lane * 16;
          async16(wls[buf ^ 1] + (tap * 4 + cg) * 2048 + cb * 1024, g);
        }
      }
      int r_local = wave + dr;
      const char* wb = wls[buf];
      const char* xrow = xls;  // + cgl*6336 + r_local*1056
      // ---- 12-step pipelined compute: step = (ds, ks, mthalf) ------------
      bf16x8 afp[2][2], bfp[2][2];
      {  // prologue: step 0 = (ds0, ks0, mh0)
        int cgl = hi;
        afp[0][0] = *(const bf16x8*)(wb + cgl * 2048 + (0 * 32 + l31) * 16);
        afp[0][1] = *(const bf16x8*)(wb + cgl * 2048 + (1 * 32 + l31) * 16);
        const char* xr = xrow + cgl * 6336 + r_local * 1056;
        bfp[0][0] = *(const bf16x8*)(xr + (0 * 32 + l31 + 0) * 16);
        bfp[0][1] = *(const bf16x8*)(xr + (1 * 32 + l31 + 0) * 16);
      }
#pragma unroll
      for (int s = 0; s < 12; ++s) {
        int mh = s & 1;
        int cura = s & 1, curb = (s >> 1) & 1;
        if (s < 11) {  // prefetch step s+1 into the other banks
          int s1 = s + 1;
          int ds1 = s1 >> 2, ks1 = (s1 >> 1) & 1, mh1 = s1 & 1;
          int cgl1 = ks1 * 2 + hi;
          const char* wt1 = wb + ds1 * 8192 + cgl1 * 2048;
          afp[s1 & 1][0] = *(const bf16x8*)(wt1 + ((mh1 * 2 + 0) * 32 + l31) * 16);
          afp[s1 & 1][1] = *(const bf16x8*)(wt1 + ((mh1 * 2 + 1) * 32 + l31) * 16);
          if (mh1 == 0) {
            const char* xr1 = xrow + cgl1 * 6336 + r_local * 1056;
            bfp[(s1 >> 1) & 1][0] = *(const bf16x8*)(xr1 + (0 * 32 + l31 + ds1) * 16);
            bfp[(s1 >> 1) & 1][1] = *(const bf16x8*)(xr1 + (1 * 32 + l31 + ds1) * 16);
          }
        }
#pragma unroll
        for (int i = 0; i < 2; ++i)
#pragma unroll
          for (int nt = 0; nt < 2; ++nt)
            acc[mh * 2 + i][nt] = __builtin_amdgcn_mfma_f32_32x32x16_bf16(
                afp[cura][i], bfp[curb][nt], acc[mh * 2 + i][nt], 0, 0, 0);
      }
      if (dr < 2) __syncthreads();  // next wls buf landed; safe to rewrite other
    }
  }

  // ---- epilogue: C/D 32x32 layout: col=lane&31, row=(r&3)+8*(r>>2)+4*hi --
  int hh = h0 + wave;
  bf16* yb = ys + (size_t)((e * 16 + b) * 128) * 4096;
#pragma unroll
  for (int mt = 0; mt < 4; ++mt) {
    float s0 = 0.f, ss0 = 0.f, s1 = 0.f, ss1 = 0.f;
#pragma unroll
    for (int nt = 0; nt < 2; ++nt) {
      int w = nt * 32 + l31;
      int pos = hh * 64 + w;
#pragma unroll
      for (int r = 0; r < 16; ++r) {
        float v = acc[mt][nt][r];
        if (r < 8) { s0 += v; ss0 += v * v; } else { s1 += v; ss1 += v * v; }
        int row = (r & 3) + 8 * (r >> 2) + 4 * hi;
        yb[(size_t)(mt * 32 + row) * 4096 + pos] = f2bf(v);
      }
    }
#pragma unroll
    for (int off = 32; off; off >>= 1) {
      s0 += __shfl_down(s0, off, 64);
      ss0 += __shfl_down(ss0, off, 64);
      s1 += __shfl_down(s1, off, 64);
      ss1 += __shfl_down(ss1, off, 64);
    }
    if (lane == 0) {
      red[wave][mt * 2][0] = s0; red[wave][mt * 2][1] = ss0;
      red[wave][mt * 2 + 1][0] = s1; red[wave][mt * 2 + 1][1] = ss1;
    }
  }
  __syncthreads();
  if (tid < 16) {
    int g = tid >> 1, which = tid & 1;
    float t = red[0][g][which] + red[1][g][which] + red[2][g][which] + red[3][g][which];
    atomicAdd(&statsE[((e * 16 + b) * 8 + g) * 2 + which], t);
  }
}

// ---------------- combine -> bf16 channels-last (octet-vec, XCD-swizzled) --
// block for batch b placed on xcd b>>1 = the XCD whose L2 saw conv's ys[.][b]
__global__ __launch_bounds__(256) void combine_cl(
    const float* __restrict__ x, const bf16* __restrict__ ys,
    const float* __restrict__ stE, const float* __restrict__ gns,
    const float* __restrict__ gnb, const float* __restrict__ wts,
    bf16* __restrict__ ccl) {
  __shared__ bf16 tile[64][132];
  int blk = blockIdx.x;
  int xcd = blk & 7;
  int k2 = blk >> 3;               // 0..127
  int b = xcd * 2 + (k2 >> 6);
  int h = k2 & 63;
  int t = threadIdx.x;
  int oct = t & 7, cq = t >> 3;        // cq in 0..31; co = cq*4 + k
  int w0 = oct * 8;
  int gidx = cq >> 2;                  // co>>4 (constant over k)
  int pid = (h >> 4) * 4 + (w0 >> 4);
  int pos = h * 64 + w0;

  float m_[8], r_[8], wt_[8];
#pragma unroll
  for (int e = 0; e < 8; ++e) {
    float S = stE[((e * 16 + b) * 8 + gidx) * 2];
    float SS = stE[((e * 16 + b) * 8 + gidx) * 2 + 1];
    float mean = S * (1.f / 65536.f);
    float var = SS * (1.f / 65536.f) - mean * mean;
    m_[e] = mean;
    r_[e] = rsqrtf(var + 1e-5f);
    wt_[e] = wts[pid * 8 + e];
  }

#pragma unroll
  for (int k = 0; k < 4; ++k) {
    int co = cq * 4 + k;
    const float* xp = x + ((size_t)(b * 128 + co) << 12) + pos;
    float v[8];
    float4 xa = *(const float4*)xp;
    float4 xb2 = *(const float4*)(xp + 4);
    v[0] = xa.x; v[1] = xa.y; v[2] = xa.z; v[3] = xa.w;
    v[4] = xb2.x; v[5] = xb2.y; v[6] = xb2.z; v[7] = xb2.w;
#pragma unroll
    for (int e = 0; e < 8; ++e) {
      uint4 u = *(const uint4*)(ys + ((size_t)((e * 16 + b) * 128 + co) << 12) + pos);
      const bf16* pv = (const bf16*)&u;
      float sc = r_[e] * gns[e * 128 + co];
      float sh = gnb[e * 128 + co] - m_[e] * sc;
#pragma unroll
      for (int j = 0; j < 8; ++j) {
        float yn = bf2f(pv[j]) * sc + sh;
        v[j] = fmaf(siluf(yn), wt_[e], v[j]);
      }
    }
#pragma unroll
    for (int j = 0; j < 8; ++j) tile[w0 + j][co] = f2bf(v[j]);
  }
  __syncthreads();
  int row = t >> 2, q = t & 3;
  char* dst = (char*)ccl + ((size_t)(b * 4096 + h * 64 + row)) * 256 + q * 64;
  const char* src = (const char*)&tile[row][0] + q * 64;
#pragma unroll
  for (int i = 0; i < 4; ++i)
    *(uint4*)(dst + i * 16) = *(const uint4*)(src + i * 16);
}

// ---------------- pw1 MFMA v2: B staged once, mtile loop -------------------
// h1[hc=512][n=65536] = w[hc][ci] @ ccl[n][ci]; grid 512 = ntile only.
__global__ __launch_bounds__(256) void pw1_mfma(
    const bf16* __restrict__ ccl, const bf16* __restrict__ wp1T,
    bf16* __restrict__ h1cl, float* __restrict__ stats1) {
  __shared__ __align__(16) char bls[32768];   // ccl tile, persistent
  __shared__ __align__(16) char ls2[34816];   // als(32K) / tile(33.8K) union
  __shared__ float red[4][2][2];
  int blk = blockIdx.x;
  int n0 = blk * 128;
  int t = threadIdx.x, lane = t & 63, wave = t >> 6;
  int quad = lane >> 4, l15 = lane & 15;
  int b = n0 >> 12;

  // ---- stage B once: [c16][r128]x16B ----
#pragma unroll
  for (int i = 0; i < 8; ++i) {
    int id = t + 256 * i;
    int r = id >> 4, c = id & 15;
    *(uint4*)(bls + c * 2048 + r * 16) =
        *(const uint4*)((const char*)ccl + (size_t)(n0 + r) * 256 + c * 16);
  }

  for (int mtile = 0; mtile < 4; ++mtile) {
    int m0 = mtile * 128;
    char* als = ls2;
#pragma unroll
    for (int i = 0; i < 8; ++i) {
      int id = t + 256 * i;
      int r = id >> 4, c = id & 15;
      *(uint4*)(als + c * 2048 + r * 16) =
          *(const uint4*)((const char*)wp1T + (size_t)(m0 + r) * 256 + c * 16);
    }
    __syncthreads();  // als (+bls on iter 0) visible

    f32x4 acc[8][2];
#pragma unroll
    for (int mt = 0; mt < 8; ++mt)
#pragma unroll
      for (int nt = 0; nt < 2; ++nt) acc[mt][nt] = (f32x4){0.f, 0.f, 0.f, 0.f};

#pragma unroll
    for (int kc = 0; kc < 4; ++kc) {
      int cgq = kc * 4 + quad;
      bf16x8 af[8];
#pragma unroll
      for (int mt = 0; mt < 8; ++mt)
        af[mt] = *(const bf16x8*)(als + cgq * 2048 + (mt * 16 + l15) * 16);
      bf16x8 bfr[2];
#pragma unroll
      for (int nt = 0; nt < 2; ++nt)
        bfr[nt] = *(const bf16x8*)(bls + cgq * 2048 + (wave * 32 + nt * 16 + l15) * 16);
#pragma unroll
      for (int mt = 0; mt < 8; ++mt)
#pragma unroll
        for (int nt = 0; nt < 2; ++nt)
          acc[mt][nt] = __builtin_amdgcn_mfma_f32_16x16x32_bf16(
              af[mt], bfr[nt], acc[mt][nt], 0, 0, 0);
    }

    __syncthreads();  // all waves done reading als before tile overwrite
    float s[2] = {0.f, 0.f}, ss[2] = {0.f, 0.f};
    bf16* tile = (bf16*)ls2;  // row stride 132 elems = 264 B
#pragma unroll
    for (int mt = 0; mt < 8; ++mt) {
      int gi = mt >> 2;
#pragma unroll
      for (int nt = 0; nt < 2; ++nt) {
        int n = wave * 32 + nt * 16 + l15;
#pragma unroll
        for (int r = 0; r < 4; ++r) {
          float v = acc[mt][nt][r];
          s[gi] += v;
          ss[gi] += v * v;
          tile[n * 132 + mt * 16 + quad * 4 + r] = f2bf(v);
        }
      }
    }
#pragma unroll
    for (int gi = 0; gi < 2; ++gi) {
#pragma unroll
      for (int off = 32; off; off >>= 1) {
        s[gi] += __shfl_down(s[gi], off, 64);
        ss[gi] += __shfl_down(ss[gi], off, 64);
      }
    }
    if (lane == 0) {
      red[wave][0][0] = s[0]; red[wave][0][1] = ss[0];
      red[wave][1][0] = s[1]; red[wave][1][1] = ss[1];
    }
    __syncthreads();  // tile + red complete
    if (t < 4) {
      int gi = t >> 1, which = t & 1;
      float v = red[0][gi][which] + red[1][gi][which] + red[2][gi][which] + red[3][gi][which];
      atomicAdd(&stats1[(b * 8 + mtile * 2 + gi) * 2 + which], v);
    }
#pragma unroll
    for (int i = 0; i < 8; ++i) {
      int id = t + 256 * i;             // 0..2047
      int r = id >> 4, q = id & 15;     // 128 rows x 16 chunks of 16B
      char* dst = (char*)h1cl + (size_t)(n0 + r) * 1024 + m0 * 2 + q * 16;
      const char* src = (const char*)tile + r * 264 + q * 16;
      *(uint4*)dst = *(const uint4*)src;
    }
    __syncthreads();  // tile copies done before next mtile's als staging
  }
}

// ---------------- dw3x3: LDS-staged GN1+SiLU tile + sliding stencil --------
// (stats1 read RAW; finalize inlined)
__global__ __launch_bounds__(256) void dw_cl(
    const bf16* __restrict__ h1cl, const float* __restrict__ w_dw,
    const float* __restrict__ st1, const float* __restrict__ gs,
    const float* __restrict__ gb, bf16* __restrict__ h2cl,
    float* __restrict__ stats2) {
  __shared__ __align__(16) bf16 tile[18 * 66 * 16];  // 38016 B
  __shared__ float red2[4][2];
  int blk = blockIdx.x;
  int ht = blk & 3, hcg = (blk >> 2) & 31, b = blk >> 7;
  int h0 = ht * 16;
  int hc0 = hcg * 16;
  int hcb = hcg >> 2;  // 64-hc GN group
  int t = threadIdx.x;

  float S1 = st1[(b * 8 + hcb) * 2], SS1 = st1[(b * 8 + hcb) * 2 + 1];
  float mean = S1 * (1.f / 262144.f);
  float var1 = SS1 * (1.f / 262144.f) - mean * mean;
  float rstd = rsqrtf(var1 + 1e-5f);
  float scale[16], shift[16];
#pragma unroll
  for (int j = 0; j < 16; ++j) {
    float g = gs[hc0 + j];
    scale[j] = rstd * g;
    shift[j] = gb[hc0 + j] - mean * rstd * g;
  }

  // ---- stage: 18 x 66 (row, wslot) pairs; wslot 0 and 65 are zero pad ----
  for (int i = 0; i < 5; ++i) {
    int idx = t + 256 * i;
    if (idx >= 1188) break;
    int row = idx / 66, wslot = idx - row * 66;
    int hh = h0 - 1 + row;
    int w = wslot - 1;
    int swz = (wslot >> 2) & 3;  // quarter swizzle base
    bf16* dst = tile + (row * 66 + wslot) * 16;
    if ((unsigned)hh < 64u && (unsigned)w < 64u) {
      const char* p = (const char*)h1cl + ((size_t)(b * 4096 + hh * 64 + w) * 512 + hc0) * 2;
      uint4 a0 = *(const uint4*)p;
      uint4 a1 = *(const uint4*)(p + 16);
      const bf16* pv = (const bf16*)&a0;
      const bf16* pv1 = (const bf16*)&a1;
      bf16 outv[16];
#pragma unroll
      for (int j = 0; j < 8; ++j)
        outv[j] = f2bf(siluf(bf2f(pv[j]) * scale[j] + shift[j]));
#pragma unroll
      for (int j = 0; j < 8; ++j)
        outv[8 + j] = f2bf(siluf(bf2f(pv1[j]) * scale[8 + j] + shift[8 + j]));
      // place logical quarter qq at physical slot (qq+swz)&3
#pragma unroll
      for (int qq = 0; qq < 4; ++qq) {
        int ph = (qq + swz) & 3;
        *(uint2*)(dst + ph * 4) = *(const uint2*)(outv + qq * 4);
      }
    } else {
      *(uint4*)dst = make_uint4(0u, 0u, 0u, 0u);
      *(uint4*)(dst + 8) = make_uint4(0u, 0u, 0u, 0u);
    }
  }
  __syncthreads();

  // ---- compute: thread = (w, quarter q of 4 hc), slide over 16 rows ----
  int w = t & 63, q = t >> 6;
  float wv[9][4];
#pragma unroll
  for (int j = 0; j < 4; ++j) {
    int hc = hc0 + q * 4 + j;
#pragma unroll
    for (int tap = 0; tap < 9; ++tap) wv[tap][j] = w_dw[hc * 9 + tap];
  }

  f32x4 win[3][3];  // [ring(row%3)][dw]
  float acc_s = 0.f, acc_ss = 0.f;

  auto ld4 = [&](int r, int dwi) -> f32x4 {
    int slot = w + dwi;
    int ph = (q + (slot >> 2)) & 3;
    const bf16* p = tile + (r * 66 + slot) * 16 + ph * 4;
    uint2 u = *(const uint2*)p;
    const bf16* pb = (const bf16*)&u;
    return (f32x4){bf2f(pb[0]), bf2f(pb[1]), bf2f(pb[2]), bf2f(pb[3])};
  };

#pragma unroll
  for (int dwi = 0; dwi < 3; ++dwi) {
    win[0][dwi] = ld4(0, dwi);
    win[1][dwi] = ld4(1, dwi);
  }
#pragma unroll
  for (int orow = 0; orow < 16; ++orow) {
    int rnew = orow + 2;
    int ringn = rnew % 3;
#pragma unroll
    for (int dwi = 0; dwi < 3; ++dwi) win[ringn][dwi] = ld4(rnew, dwi);
    f32x4 acc = (f32x4){0.f, 0.f, 0.f, 0.f};
#pragma unroll
    for (int dr = 0; dr < 3; ++dr) {
      int ring = (orow + dr) % 3;
#pragma unroll
      for (int dwi = 0; dwi < 3; ++dwi) {
#pragma unroll
        for (int j = 0; j < 4; ++j)
          acc[j] = fmaf(win[ring][dwi][j], wv[dr * 3 + dwi][j], acc[j]);
      }
    }
#pragma unroll
    for (int j = 0; j < 4; ++j) { acc_s += acc[j]; acc_ss += acc[j] * acc[j]; }
    if (!(orow & 1) && !(w & 1)) {
      int hglob = h0 + orow;
      int pos2 = (hglob >> 1) * 32 + (w >> 1);
      bf16 tmp[4];
#pragma unroll
      for (int j = 0; j < 4; ++j) tmp[j] = f2bf(acc[j]);
      *(uint2*)((char*)h2cl + ((size_t)(b * 1024 + pos2) * 512 + hc0 + q * 4) * 2) =
          *(const uint2*)tmp;
    }
  }

  // ---- stats reduction: one atomic pair per block into (b, hcb) ----
#pragma unroll
  for (int off = 32; off; off >>= 1) {
    acc_s += __shfl_down(acc_s, off, 64);
    acc_ss += __shfl_down(acc_ss, off, 64);
  }
  int wave = t >> 6;
  if ((t & 63) == 0) { red2[wave][0] = acc_s; red2[wave][1] = acc_ss; }
  __syncthreads();
  if (t < 2) {
    float v = red2[0][t] + red2[1][t] + red2[2][t] + red2[3][t];
    atomicAdd(&stats2[(b * 8 + hcb) * 2 + t], v);
  }
}

// ---------------- pw2 MFMA (GN2+SiLU fused on bls staging) -----------------
// h3[co=128][n=16384] = w[co][hc] @ silu(GN2(h2raw))[n][hc]
__global__ __launch_bounds__(256) void pw2_mfma(
    const bf16* __restrict__ h2, const bf16* __restrict__ wp2T,
    const float* __restrict__ st2, const float* __restrict__ gs2,
    const float* __restrict__ gb2, float* __restrict__ h3,
    float* __restrict__ stats3) {
  __shared__ __align__(16) char als[2][8192];
  __shared__ __align__(16) char bls[2][4096];
  __shared__ float red[4][8][2];
  int blk = blockIdx.x;
  int n0 = blk * 64;
  int b = n0 >> 10, posb = n0 & 1023;
  int t = threadIdx.x, lane = t & 63, wave = t >> 6;
  int quad = lane >> 4, l15 = lane & 15;
  int wbase = wave * 16;
  int c4 = t >> 6, r = t & 63;

  // normalize+silu h2 octet (kc,c4) for row n0+r, write 16B to dst
  auto load_bls = [&](char* dst, int kc) {
    int hc0 = (kc * 4 + c4) * 8;
    int g = hc0 >> 6;
    float S = st2[(b * 8 + g) * 2], SS = st2[(b * 8 + g) * 2 + 1];
    float mean = S * (1.f / 262144.f);
    float rstd = rsqrtf(SS * (1.f / 262144.f) - mean * mean + 1e-5f);
    uint4 u = *(const uint4*)((const char*)h2 + (size_t)(n0 + r) * 1024 +
                              (size_t)(kc * 4 + c4) * 16);
    const bf16* pv = (const bf16*)&u;
    bf16 outv[8];
#pragma unroll
    for (int j = 0; j < 8; ++j) {
      float xv = bf2f(pv[j]);
      xv = (xv - mean) * rstd * gs2[hc0 + j] + gb2[hc0 + j];
      outv[j] = f2bf(siluf(xv));
    }
    *(uint4*)dst = *(const uint4*)outv;
  };

  f32x4 acc[8];
#pragma unroll
  for (int mt = 0; mt < 8; ++mt) acc[mt] = (f32x4){0.f, 0.f, 0.f, 0.f};

  {
#pragma unroll
    for (int i = 0; i < 2; ++i) {
      int id = t + 256 * i;
      int cc = id >> 7, rr = id & 127;
      *(uint4*)(als[0] + cc * 2048 + rr * 16) =
          *(const uint4*)((const char*)wp2T + (size_t)rr * 1024 + cc * 16);
    }
    load_bls(bls[0] + c4 * 1024 + r * 16, 0);
  }
#pragma unroll
  for (int kc = 0; kc < 16; ++kc) {
    __syncthreads();
    if (kc + 1 < 16) {
      int nb = (kc + 1) & 1;
#pragma unroll
      for (int i = 0; i < 2; ++i) {
        int id = t + 256 * i;
        int cc = id >> 7, rr = id & 127;
        *(uint4*)(als[nb] + cc * 2048 + rr * 16) =
            *(const uint4*)((const char*)wp2T + (size_t)rr * 1024 + ((kc + 1) * 4 + cc) * 16);
      }
      load_bls(bls[nb] + c4 * 1024 + r * 16, kc + 1);
    }
    int buf = kc & 1;
    bf16x8 bf1 = *(const bf16x8*)(bls[buf] + quad * 1024 + (wbase + l15) * 16);
#pragma unroll
    for (int mt = 0; mt < 8; ++mt) {
      bf16x8 af = *(const bf16x8*)(als[buf] + quad * 2048 + (mt * 16 + l15) * 16);
      acc[mt] = __builtin_amdgcn_mfma_f32_16x16x32_bf16(af, bf1, acc[mt], 0, 0, 0);
    }
  }

#pragma unroll
  for (int mt = 0; mt < 8; ++mt) {
    float s = 0.f, ss = 0.f;
    int pos = posb + wbase + l15;
#pragma unroll
    for (int rr = 0; rr < 4; ++rr) {
      float v = acc[mt][rr];
      s += v;
      ss += v * v;
      int co = mt * 16 + quad * 4 + rr;
      h3[(size_t)(b * 128 + co) * 1024 + pos] = v;
    }
#pragma unroll
    for (int off = 32; off; off >>= 1) {
      s += __shfl_down(s, off, 64);
      ss += __shfl_down(ss, off, 64);
    }
    if (lane == 0) { red[wave][mt][0] = s; red[wave][mt][1] = ss; }
  }
  __syncthreads();
  if (t < 16) {
    int mt = t >> 1, which = t & 1;
    float v = red[0][mt][which] + red[1][mt][which] + red[2][mt][which] + red[3][mt][which];
    atomicAdd(&stats3[(b * 8 + mt) * 2 + which], v);
  }
}

// ---------------- final GN+SiLU -> d_out (fp32, float4) --------------------
__global__ void out_kernel(const float* __restrict__ h3, const float* __restrict__ stats,
                           const float* __restrict__ gs, const float* __restrict__ gb,
                           float* __restrict__ out) {
  const int total4 = (B_ * COUT_ * 1024) >> 2;
  for (int i4 = blockIdx.x * blockDim.x + threadIdx.x; i4 < total4;
       i4 += gridDim.x * blockDim.x) {
    int idx = i4 << 2;
    int c = (idx >> 10) & 127;     // uniform over the 4 elements (1024%4==0)
    int b = idx >> 17;
    int bg = b * 8 + (c >> 4);
    float S = stats[bg * 2], SS = stats[bg * 2 + 1];
    float mean = S * (1.f / 16384.f);
    float var = SS * (1.f / 16384.f) - mean * mean;
    float rstd = rsqrtf(var + 1e-5f);
    float sc = rstd * gs[c];
    float sh = gb[c] - mean * sc;
    float4 hv = *(const float4*)(h3 + idx);
    float4 res;
    res.x = siluf(hv.x * sc + sh);
    res.y = siluf(hv.y * sc + sh);
    res.z = siluf(hv.z * sc + sh);
    res.w = siluf(hv.w * sc + sh);
    *(float4*)(out + idx) = res;
  }
}

extern "C" void kernel_launch(void* const* d_in, const int* in_sizes, int n_in,
                              void* d_out, int out_size, void* d_ws, size_t ws_size,
                              hipStream_t stream) {
  const float* x = (const float*)d_in[0];
  const float* w_exp = (const float*)d_in[1];
  const float* gn_exp_s = (const float*)d_in[2];
  const float* gn_exp_b = (const float*)d_in[3];
  const float* w1 = (const float*)d_in[4];
  const float* b1 = (const float*)d_in[5];
  const float* w2 = (const float*)d_in[6];
  const float* b2 = (const float*)d_in[7];
  const float* w_pw1 = (const float*)d_in[8];
  const float* gn1_s = (const float*)d_in[9];
  const float* gn1_b = (const float*)d_in[10];
  const float* w_dw = (const float*)d_in[11];
  const float* gn2_s = (const float*)d_in[12];
  const float* gn2_b = (const float*)d_in[13];
  const float* w_pw2 = (const float*)d_in[14];
  const float* gn3_s = (const float*)d_in[15];
  const float* gn3_b = (const float*)d_in[16];

  char* ws = (char*)d_ws;
  const size_t WP1T_OFF = 16384;
  const size_t WP2T_OFF = WP1T_OFF + 131072;
  const size_t XT_OFF = WP2T_OFF + 131072;                 // 278528
  const size_t WT_OFF = XT_OFF + 16777216;                 // 17055744
  const size_t YS_OFF = WT_OFF + 2359296;                  // 19415040
  const size_t NEEDED = YS_OFF + 134217728;                // 153632768
  if (ws_size < NEEDED) return;

  float* wts = (float*)ws;
  float* stats1 = (float*)(ws + 1024);
  float* stats2 = (float*)(ws + 2048);
  float* stats3 = (float*)(ws + 3072);
  float* statsE = (float*)(ws + 4096);
  bf16* wp1T = (bf16*)(ws + WP1T_OFF);
  bf16* wp2T = (bf16*)(ws + WP2T_OFF);
  bf16* xT = (bf16*)(ws + XT_OFF);
  bf16* ccl = (bf16*)(ws + XT_OFF);
  bf16* wT = (bf16*)(ws + WT_OFF);
  bf16* ys = (bf16*)(ws + YS_OFF);
  bf16* h1cl = (bf16*)(ws + YS_OFF);
  bf16* h2cl = (bf16*)(ws + YS_OFF + 67108864);
  float* h3 = (float*)(ws + YS_OFF + 83886080);

  hipMemsetAsync(ws, 0, 16384, stream);
  prep_kernel<<<6145, 256, 0, stream>>>(x, xT, w_exp, wT, w_pw1, w_pw2, wp1T, wp2T,
                                        w1, b1, w2, b2, wts);
  conv_mfma<<<E_ * B_ * 16, 256, 0, stream>>>(xT, wT, statsE, ys);
  combine_cl<<<B_ * 64, 256, 0, stream>>>(x, ys, statsE, gn_exp_s, gn_exp_b, wts, ccl);
  pw1_mfma<<<512, 256, 0, stream>>>(ccl, wp1T, h1cl, stats1);
  dw_cl<<<B_ * 32 * 4, 256, 0, stream>>>(h1cl, w_dw, stats1, gn1_s, gn1_b, h2cl, stats2);
  pw2_mfma<<<256, 256, 0, stream>>>(h2cl, wp2T, stats2, gn2_s, gn2_b, h3, stats3);
  out_kernel<<<1024, 256, 0, stream>>>(h3, stats3, gn3_s, gn3_b, (float*)d_out);
}

// Round 10
// 432.868 us; speedup vs baseline: 1.1833x; 1.0110x over previous
//
#include <hip/hip_runtime.h>
#include <hip/hip_bf16.h>

// ---------------------------------------------------------------------------
// PCELayer R15 = R14 with measurement + three riskless cuts:
//  - conv_mfma split into 2 dispatches (e_base 0/4) so each entry ~76us ->
//    any non-conv kernel >76us surfaces in the top-5 next round (the 285us
//    non-conv stack has resisted two structural rounds; must locate it).
//  - hipMemsetAsync removed; stats head [1024,16384) zeroed in prep's gate
//    block (disjoint from wts, ordered before all stats consumers).
//  - pw2_mfma grid 256->512 (co halved per block): was 1 block/CU (12.5%
//    occupancy) on a latency-bound staged loop; now 2 blocks/CU. bls staged
//    twice (+16.8MB L3-hot) in exchange.
// conv/combine/pw1/dw unchanged from R14 (conv at its 149.5us pareto point).
// Workspace (153.6 MB): head 16K | wp1T 128K | wp2T 128K | XT 16.8M (->ccl)
//   | WT 2.4M | YS 134.2M (-> h1cl 67M | h2cl 16.8M | h3 8.4M)
// ---------------------------------------------------------------------------

#define B_ 16
#define CIN_ 128
#define COUT_ 128
#define H_ 64
#define W_ 64
#define HW_ 4096
#define E_ 8
#define FF_ 8
#define GC_ 32
#define HID_ 64
#define HC_ 512

typedef __hip_bfloat16 bf16;
typedef __bf16 bf16x8 __attribute__((ext_vector_type(8)));
typedef float f32x4 __attribute__((ext_vector_type(4)));
typedef float f32x16 __attribute__((ext_vector_type(16)));

__device__ __forceinline__ float siluf(float v) {
  // v * sigmoid(v) with 1-instruction v_rcp_f32 (precise div is ~10 instrs)
  return v * __builtin_amdgcn_rcpf(1.f + __expf(-v));
}
__device__ __forceinline__ float bf2f(bf16 v) { return __bfloat162float(v); }
__device__ __forceinline__ bf16 f2bf(float v) { return __float2bfloat16(v); }

// async 16B/lane global->LDS copy. lds must be the wave-uniform segment base;
// HW writes lane i at lds + i*16. g is the per-lane global address.
__device__ __forceinline__ void async16(void* lds, const void* g) {
  __builtin_amdgcn_global_load_lds(
      (const __attribute__((address_space(1))) unsigned int*)g,
      (__attribute__((address_space(3))) unsigned int*)lds, 16, 0, 0);
}

// ---------------- merged prep: xt | wt | wpT | gate+statszero ---------------
// blk <1024: x->xT transpose; <5632: w_exp->wT; <6144: pw weights;
// ==6144: zero stats head + gate
__global__ __launch_bounds__(256) void prep_kernel(
    const float* __restrict__ x, bf16* __restrict__ xT,
    const float* __restrict__ w_exp, bf16* __restrict__ wT,
    const float* __restrict__ w_pw1, const float* __restrict__ w_pw2,
    bf16* __restrict__ wp1T, bf16* __restrict__ wp2T,
    const float* __restrict__ w1, const float* __restrict__ b1,
    const float* __restrict__ w2, const float* __restrict__ b2,
    float* __restrict__ wts) {
  __shared__ float t[128][65];
  int blk = blockIdx.x;
  int tid = threadIdx.x;

  if (blk < 1024) {
    // ---- xt: x -> channels-last bf16 ----
    int b = blk >> 6, h = blk & 63;
    int w = tid & 63, c4 = tid >> 6;
    const float* xb = x + ((size_t)(b * 128) * 64 + h) * 64;
#pragma unroll 4
    for (int rep = 0; rep < 32; ++rep) {
      int ci = rep * 4 + c4;
      t[ci][w] = xb[(size_t)ci * HW_ + w];
    }
    __syncthreads();
    bf16* dst = xT + (size_t)(b * 64 + h) * 8192;
#pragma unroll 4
    for (int rep = 0; rep < 32; ++rep) {
      int o = rep * 256 + tid;
      int cg = o >> 9, w2 = (o >> 3) & 63, lo = o & 7;
      dst[o] = f2bf(t[cg * 8 + lo][w2]);
    }
  } else if (blk < 5632) {
    // ---- wt: w_exp -> wT bf16 ----
    int idx = (blk - 1024) * 256 + tid;
    if (idx < 1179648) {
      int lo = idx & 7;
      int co = (idx >> 3) & 127;
      int cg = (idx >> 10) & 15;
      int rest = idx >> 14;
      int tap = rest % 9, e = rest / 9;
      int ci = cg * 8 + lo;
      wT[idx] = f2bf(w_exp[(((size_t)(e * 128 + co) * 128 + ci) * 9) + tap]);
    }
  } else if (blk < 6144) {
    // ---- wpT: pw weights fp32 -> bf16 ----
    int idx = (blk - 5632) * 256 + tid;
    if (idx < 65536) wp1T[idx] = f2bf(w_pw1[idx]);
    else wp2T[idx - 65536] = f2bf(w_pw2[idx - 65536]);
  } else {
    // ---- zero stats head [1024,16384): 960 uint4 ----
    uint4* z = (uint4*)((char*)wts + 1024);
    for (int i = tid; i < 960; i += 256) z[i] = make_uint4(0u, 0u, 0u, 0u);
    // ---- gate ----
    int p = tid;
    if (p >= 16) return;
    int i = p >> 2, j = p & 3;
    float cy = (i + 0.5f) * 0.25f;
    float cx = (j + 0.5f) * 0.25f;
    float feats[GC_];
#pragma unroll
    for (int f = 0; f < FF_; ++f) {
      float fr = 3.14159265358979f * (float)(1 << f);
      float ay = cy * fr, ax = cx * fr;
      feats[f] = sinf(ay);
      feats[FF_ + f] = cosf(ay);
      feats[2 * FF_ + f] = sinf(ax);
      feats[3 * FF_ + f] = cosf(ax);
    }
    float hid[HID_];
    for (int k = 0; k < HID_; ++k) {
      float a = b1[k];
#pragma unroll
      for (int m = 0; m < GC_; ++m) a = fmaf(feats[m], w1[m * HID_ + k], a);
      hid[k] = siluf(a);
    }
    float lg[E_];
    float mx = -1e30f;
#pragma unroll
    for (int e = 0; e < E_; ++e) {
      float a = b2[e];
      for (int k = 0; k < HID_; ++k) a = fmaf(hid[k], w2[k * E_ + e], a);
      lg[e] = a;
      mx = fmaxf(mx, a);
    }
    float s = 0.f;
#pragma unroll
    for (int e = 0; e < E_; ++e) { lg[e] = __expf(lg[e] - mx); s += lg[e]; }
    float inv = 1.f / s;
#pragma unroll
    for (int e = 0; e < E_; ++e) wts[p * E_ + e] = lg[e] * inv;
  }
}

// ---------------- expert conv via MFMA (R10 v7, split on e_base) -----------
// grid 1024 per dispatch: covers experts e_base..e_base+3.
__global__ __launch_bounds__(256, 2) void conv_mfma(
    const bf16* __restrict__ xT, const bf16* __restrict__ wT,
    float* __restrict__ statsE, bf16* __restrict__ ys, int e_base) {
  __shared__ __align__(16) char xls[4 * 6336];     // [cg4][r6][slot66]x16B, padded
  __shared__ __align__(16) char wls[2][3 * 8192];  // dbuf [tap3][cg4][co128]x16B
  __shared__ float red[4][8][2];

  int blk = blockIdx.x;
  // XCD swizzle: xcd = blk&7 -> b = xcd*2 + bsub. Bijective over 1024 blocks.
  int xcd = blk & 7;
  int r2 = blk >> 3;                  // 0..127
  int b = xcd * 2 + (r2 & 1);
  int rest = r2 >> 1;                 // 0..63
  int rt = rest & 15, e = e_base + (rest >> 4);

  int tid = threadIdx.x, lane = tid & 63, wave = tid >> 6;
  int hi = lane >> 5, l31 = lane & 31;
  int h0 = rt * 4;

  // ---- one-time zeroing: edge slots (0,65) of all rows; invalid halo rows -
  if (tid < 48) {
    int cg = tid / 12, rem = tid % 12;
    int r = rem >> 1, edge = rem & 1;
    *(uint4*)(xls + cg * 6336 + r * 1056 + edge * 1040) = make_uint4(0u, 0u, 0u, 0u);
  }
  int rbad = (rt == 0) ? 0 : (rt == 15 ? 5 : -1);
  if (rbad >= 0) {
    int cg = tid >> 6, slot = (tid & 63) + 1;
    *(uint4*)(xls + cg * 6336 + rbad * 1056 + slot * 16) = make_uint4(0u, 0u, 0u, 0u);
  }

  f32x16 acc[4][2];
#pragma unroll
  for (int mt = 0; mt < 4; ++mt)
#pragma unroll
    for (int nt = 0; nt < 2; ++nt)
#pragma unroll
      for (int r = 0; r < 16; ++r) acc[mt][nt][r] = 0.f;

  for (int q = 0; q < 4; ++q) {
    if (q) __syncthreads();  // all waves done reading xls/wls[0] last quarter
    // ---- stage x quarter: wave handles cg=wave, valid rows (slots 1..64) --
    {
      int cg = wave;
#pragma unroll
      for (int r = 0; r < 6; ++r) {
        int h = h0 - 1 + r;
        if ((unsigned)h < 64u) {
          const char* g = (const char*)xT +
              ((size_t)((b * 64 + h) * 16) + q * 4 + cg) * 1024 + lane * 16;
          async16(xls + cg * 6336 + r * 1056 + 16, g);
        }
      }
    }
    // ---- stage weights for dr=0 (taps 0..2 of this quarter) -> buf0 ------
#pragma unroll
    for (int s = 0; s < 6; ++s) {
      int seg = wave * 6 + s;            // tap(3) x cg(4) x cb(2)
      int tap = seg >> 3, rem = seg & 7;
      int cg = rem >> 1, cb = rem & 1;
      const char* g = (const char*)wT +
          ((size_t)(((e * 9 + tap) * 16) + q * 4 + cg) * 128 + cb * 64) * 16 + lane * 16;
      async16(wls[0] + (tap * 4 + cg) * 2048 + cb * 1024, g);
    }
    __syncthreads();  // drains vmcnt(0): x quarter + dr0 weights ready

    for (int dr = 0; dr < 3; ++dr) {
      int buf = dr & 1;
      if (dr < 2) {
        // prefetch next dr group's 3 taps into the other buffer; landing
        // guaranteed by the barrier at the end of this window.
#pragma unroll
        for (int s = 0; s < 6; ++s) {
          int seg = wave * 6 + s;
          int tap = seg >> 3, rem = seg & 7;
          int cg = rem >> 1, cb = rem & 1;
          const char* g = (const char*)wT +
              ((size_t)(((e * 9 + (dr + 1) * 3 + tap) * 16) + q * 4 + cg) * 128 + cb * 64) * 16 +
              lane * 16;
          async16(wls[buf ^ 1] + (tap * 4 + cg) * 2048 + cb * 1024, g);
        }
      }
      int r_local = wave + dr;
      const char* wb = wls[buf];
      const char* xrow = xls;  // + cgl*6336 + r_local*1056
      // ---- 12-step pipelined compute: step = (ds, ks, mthalf) ------------
      bf16x8 afp[2][2], bfp[2][2];
      {  // prologue: step 0 = (ds0, ks0, mh0)
        int cgl = hi;
        afp[0][0] = *(const bf16x8*)(wb + cgl * 2048 + (0 * 32 + l31) * 16);
        afp[0][1] = *(const bf16x8*)(wb + cgl * 2048 + (1 * 32 + l31) * 16);
        const char* xr = xrow + cgl * 6336 + r_local * 1056;
        bfp[0][0] = *(const bf16x8*)(xr + (0 * 32 + l31 + 0) * 16);
        bfp[0][1] = *(const bf16x8*)(xr + (1 * 32 + l31 + 0) * 16);
      }
#pragma unroll
      for (int s = 0; s < 12; ++s) {
        int mh = s & 1;
        int cura = s & 1, curb = (s >> 1) & 1;
        if (s < 11) {  // prefetch step s+1 into the other banks
          int s1 = s + 1;
          int ds1 = s1 >> 2, ks1 = (s1 >> 1) & 1, mh1 = s1 & 1;
          int cgl1 = ks1 * 2 + hi;
          const char* wt1 = wb + ds1 * 8192 + cgl1 * 2048;
          afp[s1 & 1][0] = *(const bf16x8*)(wt1 + ((mh1 * 2 + 0) * 32 + l31) * 16);
          afp[s1 & 1][1] = *(const bf16x8*)(wt1 + ((mh1 * 2 + 1) * 32 + l31) * 16);
          if (mh1 == 0) {
            const char* xr1 = xrow + cgl1 * 6336 + r_local * 1056;
            bfp[(s1 >> 1) & 1][0] = *(const bf16x8*)(xr1 + (0 * 32 + l31 + ds1) * 16);
            bfp[(s1 >> 1) & 1][1] = *(const bf16x8*)(xr1 + (1 * 32 + l31 + ds1) * 16);
          }
        }
#pragma unroll
        for (int i = 0; i < 2; ++i)
#pragma unroll
          for (int nt = 0; nt < 2; ++nt)
            acc[mh * 2 + i][nt] = __builtin_amdgcn_mfma_f32_32x32x16_bf16(
                afp[cura][i], bfp[curb][nt], acc[mh * 2 + i][nt], 0, 0, 0);
      }
      if (dr < 2) __syncthreads();  // next wls buf landed; safe to rewrite other
    }
  }

  // ---- epilogue: C/D 32x32 layout: col=lane&31, row=(r&3)+8*(r>>2)+4*hi --
  int hh = h0 + wave;
  bf16* yb = ys + (size_t)((e * 16 + b) * 128) * 4096;
#pragma unroll
  for (int mt = 0; mt < 4; ++mt) {
    float s0 = 0.f, ss0 = 0.f, s1 = 0.f, ss1 = 0.f;
#pragma unroll
    for (int nt = 0; nt < 2; ++nt) {
      int w = nt * 32 + l31;
      int pos = hh * 64 + w;
#pragma unroll
      for (int r = 0; r < 16; ++r) {
        float v = acc[mt][nt][r];
        if (r < 8) { s0 += v; ss0 += v * v; } else { s1 += v; ss1 += v * v; }
        int row = (r & 3) + 8 * (r >> 2) + 4 * hi;
        yb[(size_t)(mt * 32 + row) * 4096 + pos] = f2bf(v);
      }
    }
#pragma unroll
    for (int off = 32; off; off >>= 1) {
      s0 += __shfl_down(s0, off, 64);
      ss0 += __shfl_down(ss0, off, 64);
      s1 += __shfl_down(s1, off, 64);
      ss1 += __shfl_down(ss1, off, 64);
    }
    if (lane == 0) {
      red[wave][mt * 2][0] = s0; red[wave][mt * 2][1] = ss0;
      red[wave][mt * 2 + 1][0] = s1; red[wave][mt * 2 + 1][1] = ss1;
    }
  }
  __syncthreads();
  if (tid < 16) {
    int g = tid >> 1, which = tid & 1;
    float t = red[0][g][which] + red[1][g][which] + red[2][g][which] + red[3][g][which];
    atomicAdd(&statsE[((e * 16 + b) * 8 + g) * 2 + which], t);
  }
}

// ---------------- combine -> bf16 channels-last (octet-vec, XCD-swizzled) --
__global__ __launch_bounds__(256) void combine_cl(
    const float* __restrict__ x, const bf16* __restrict__ ys,
    const float* __restrict__ stE, const float* __restrict__ gns,
    const float* __restrict__ gnb, const float* __restrict__ wts,
    bf16* __restrict__ ccl) {
  __shared__ bf16 tile[64][132];
  int blk = blockIdx.x;
  int xcd = blk & 7;
  int k2 = blk >> 3;               // 0..127
  int b = xcd * 2 + (k2 >> 6);
  int h = k2 & 63;
  int t = threadIdx.x;
  int oct = t & 7, cq = t >> 3;        // cq in 0..31; co = cq*4 + k
  int w0 = oct * 8;
  int gidx = cq >> 2;                  // co>>4 (constant over k)
  int pid = (h >> 4) * 4 + (w0 >> 4);
  int pos = h * 64 + w0;

  float m_[8], r_[8], wt_[8];
#pragma unroll
  for (int e = 0; e < 8; ++e) {
    float S = stE[((e * 16 + b) * 8 + gidx) * 2];
    float SS = stE[((e * 16 + b) * 8 + gidx) * 2 + 1];
    float mean = S * (1.f / 65536.f);
    float var = SS * (1.f / 65536.f) - mean * mean;
    m_[e] = mean;
    r_[e] = rsqrtf(var + 1e-5f);
    wt_[e] = wts[pid * 8 + e];
  }

#pragma unroll
  for (int k = 0; k < 4; ++k) {
    int co = cq * 4 + k;
    const float* xp = x + ((size_t)(b * 128 + co) << 12) + pos;
    float v[8];
    float4 xa = *(const float4*)xp;
    float4 xb2 = *(const float4*)(xp + 4);
    v[0] = xa.x; v[1] = xa.y; v[2] = xa.z; v[3] = xa.w;
    v[4] = xb2.x; v[5] = xb2.y; v[6] = xb2.z; v[7] = xb2.w;
#pragma unroll
    for (int e = 0; e < 8; ++e) {
      uint4 u = *(const uint4*)(ys + ((size_t)((e * 16 + b) * 128 + co) << 12) + pos);
      const bf16* pv = (const bf16*)&u;
      float sc = r_[e] * gns[e * 128 + co];
      float sh = gnb[e * 128 + co] - m_[e] * sc;
#pragma unroll
      for (int j = 0; j < 8; ++j) {
        float yn = bf2f(pv[j]) * sc + sh;
        v[j] = fmaf(siluf(yn), wt_[e], v[j]);
      }
    }
#pragma unroll
    for (int j = 0; j < 8; ++j) tile[w0 + j][co] = f2bf(v[j]);
  }
  __syncthreads();
  int row = t >> 2, q = t & 3;
  char* dst = (char*)ccl + ((size_t)(b * 4096 + h * 64 + row)) * 256 + q * 64;
  const char* src = (const char*)&tile[row][0] + q * 64;
#pragma unroll
  for (int i = 0; i < 4; ++i)
    *(uint4*)(dst + i * 16) = *(const uint4*)(src + i * 16);
}

// ---------------- pw1 MFMA v2: B staged once, mtile loop -------------------
// h1[hc=512][n=65536] = w[hc][ci] @ ccl[n][ci]; grid 512 = ntile only.
__global__ __launch_bounds__(256) void pw1_mfma(
    const bf16* __restrict__ ccl, const bf16* __restrict__ wp1T,
    bf16* __restrict__ h1cl, float* __restrict__ stats1) {
  __shared__ __align__(16) char bls[32768];   // ccl tile, persistent
  __shared__ __align__(16) char ls2[34816];   // als(32K) / tile(33.8K) union
  __shared__ float red[4][2][2];
  int blk = blockIdx.x;
  int n0 = blk * 128;
  int t = threadIdx.x, lane = t & 63, wave = t >> 6;
  int quad = lane >> 4, l15 = lane & 15;
  int b = n0 >> 12;

  // ---- stage B once: [c16][r128]x16B ----
#pragma unroll
  for (int i = 0; i < 8; ++i) {
    int id = t + 256 * i;
    int r = id >> 4, c = id & 15;
    *(uint4*)(bls + c * 2048 + r * 16) =
        *(const uint4*)((const char*)ccl + (size_t)(n0 + r) * 256 + c * 16);
  }

  for (int mtile = 0; mtile < 4; ++mtile) {
    int m0 = mtile * 128;
    char* als = ls2;
#pragma unroll
    for (int i = 0; i < 8; ++i) {
      int id = t + 256 * i;
      int r = id >> 4, c = id & 15;
      *(uint4*)(als + c * 2048 + r * 16) =
          *(const uint4*)((const char*)wp1T + (size_t)(m0 + r) * 256 + c * 16);
    }
    __syncthreads();  // als (+bls on iter 0) visible

    f32x4 acc[8][2];
#pragma unroll
    for (int mt = 0; mt < 8; ++mt)
#pragma unroll
      for (int nt = 0; nt < 2; ++nt) acc[mt][nt] = (f32x4){0.f, 0.f, 0.f, 0.f};

#pragma unroll
    for (int kc = 0; kc < 4; ++kc) {
      int cgq = kc * 4 + quad;
      bf16x8 af[8];
#pragma unroll
      for (int mt = 0; mt < 8; ++mt)
        af[mt] = *(const bf16x8*)(als + cgq * 2048 + (mt * 16 + l15) * 16);
      bf16x8 bfr[2];
#pragma unroll
      for (int nt = 0; nt < 2; ++nt)
        bfr[nt] = *(const bf16x8*)(bls + cgq * 2048 + (wave * 32 + nt * 16 + l15) * 16);
#pragma unroll
      for (int mt = 0; mt < 8; ++mt)
#pragma unroll
        for (int nt = 0; nt < 2; ++nt)
          acc[mt][nt] = __builtin_amdgcn_mfma_f32_16x16x32_bf16(
              af[mt], bfr[nt], acc[mt][nt], 0, 0, 0);
    }

    __syncthreads();  // all waves done reading als before tile overwrite
    float s[2] = {0.f, 0.f}, ss[2] = {0.f, 0.f};
    bf16* tile = (bf16*)ls2;  // row stride 132 elems = 264 B
#pragma unroll
    for (int mt = 0; mt < 8; ++mt) {
      int gi = mt >> 2;
#pragma unroll
      for (int nt = 0; nt < 2; ++nt) {
        int n = wave * 32 + nt * 16 + l15;
#pragma unroll
        for (int r = 0; r < 4; ++r) {
          float v = acc[mt][nt][r];
          s[gi] += v;
          ss[gi] += v * v;
          tile[n * 132 + mt * 16 + quad * 4 + r] = f2bf(v);
        }
      }
    }
#pragma unroll
    for (int gi = 0; gi < 2; ++gi) {
#pragma unroll
      for (int off = 32; off; off >>= 1) {
        s[gi] += __shfl_down(s[gi], off, 64);
        ss[gi] += __shfl_down(ss[gi], off, 64);
      }
    }
    if (lane == 0) {
      red[wave][0][0] = s[0]; red[wave][0][1] = ss[0];
      red[wave][1][0] = s[1]; red[wave][1][1] = ss[1];
    }
    __syncthreads();  // tile + red complete
    if (t < 4) {
      int gi = t >> 1, which = t & 1;
      float v = red[0][gi][which] + red[1][gi][which] + red[2][gi][which] + red[3][gi][which];
      atomicAdd(&stats1[(b * 8 + mtile * 2 + gi) * 2 + which], v);
    }
#pragma unroll
    for (int i = 0; i < 8; ++i) {
      int id = t + 256 * i;             // 0..2047
      int r = id >> 4, q = id & 15;     // 128 rows x 16 chunks of 16B
      char* dst = (char*)h1cl + (size_t)(n0 + r) * 1024 + m0 * 2 + q * 16;
      const char* src = (const char*)tile + r * 264 + q * 16;
      *(uint4*)dst = *(const uint4*)src;
    }
    __syncthreads();  // tile copies done before next mtile's als staging
  }
}

// ---------------- dw3x3: LDS-staged GN1+SiLU tile + sliding stencil --------
// (stats1 read RAW; finalize inlined)
__global__ __launch_bounds__(256) void dw_cl(
    const bf16* __restrict__ h1cl, const float* __restrict__ w_dw,
    const float* __restrict__ st1, const float* __restrict__ gs,
    const float* __restrict__ gb, bf16* __restrict__ h2cl,
    float* __restrict__ stats2) {
  __shared__ __align__(16) bf16 tile[18 * 66 * 16];  // 38016 B
  __shared__ float red2[4][2];
  int blk = blockIdx.x;
  int ht = blk & 3, hcg = (blk >> 2) & 31, b = blk >> 7;
  int h0 = ht * 16;
  int hc0 = hcg * 16;
  int hcb = hcg >> 2;  // 64-hc GN group
  int t = threadIdx.x;

  float S1 = st1[(b * 8 + hcb) * 2], SS1 = st1[(b * 8 + hcb) * 2 + 1];
  float mean = S1 * (1.f / 262144.f);
  float var1 = SS1 * (1.f / 262144.f) - mean * mean;
  float rstd = rsqrtf(var1 + 1e-5f);
  float scale[16], shift[16];
#pragma unroll
  for (int j = 0; j < 16; ++j) {
    float g = gs[hc0 + j];
    scale[j] = rstd * g;
    shift[j] = gb[hc0 + j] - mean * rstd * g;
  }

  // ---- stage: 18 x 66 (row, wslot) pairs; wslot 0 and 65 are zero pad ----
  for (int i = 0; i < 5; ++i) {
    int idx = t + 256 * i;
    if (idx >= 1188) break;
    int row = idx / 66, wslot = idx - row * 66;
    int hh = h0 - 1 + row;
    int w = wslot - 1;
    int swz = (wslot >> 2) & 3;  // quarter swizzle base
    bf16* dst = tile + (row * 66 + wslot) * 16;
    if ((unsigned)hh < 64u && (unsigned)w < 64u) {
      const char* p = (const char*)h1cl + ((size_t)(b * 4096 + hh * 64 + w) * 512 + hc0) * 2;
      uint4 a0 = *(const uint4*)p;
      uint4 a1 = *(const uint4*)(p + 16);
      const bf16* pv = (const bf16*)&a0;
      const bf16* pv1 = (const bf16*)&a1;
      bf16 outv[16];
#pragma unroll
      for (int j = 0; j < 8; ++j)
        outv[j] = f2bf(siluf(bf2f(pv[j]) * scale[j] + shift[j]));
#pragma unroll
      for (int j = 0; j < 8; ++j)
        outv[8 + j] = f2bf(siluf(bf2f(pv1[j]) * scale[8 + j] + shift[8 + j]));
      // place logical quarter qq at physical slot (qq+swz)&3
#pragma unroll
      for (int qq = 0; qq < 4; ++qq) {
        int ph = (qq + swz) & 3;
        *(uint2*)(dst + ph * 4) = *(const uint2*)(outv + qq * 4);
      }
    } else {
      *(uint4*)dst = make_uint4(0u, 0u, 0u, 0u);
      *(uint4*)(dst + 8) = make_uint4(0u, 0u, 0u, 0u);
    }
  }
  __syncthreads();

  // ---- compute: thread = (w, quarter q of 4 hc), slide over 16 rows ----
  int w = t & 63, q = t >> 6;
  float wv[9][4];
#pragma unroll
  for (int j = 0; j < 4; ++j) {
    int hc = hc0 + q * 4 + j;
#pragma unroll
    for (int tap = 0; tap < 9; ++tap) wv[tap][j] = w_dw[hc * 9 + tap];
  }

  f32x4 win[3][3];  // [ring(row%3)][dw]
  float acc_s = 0.f, acc_ss = 0.f;

  auto ld4 = [&](int r, int dwi) -> f32x4 {
    int slot = w + dwi;
    int ph = (q + (slot >> 2)) & 3;
    const bf16* p = tile + (r * 66 + slot) * 16 + ph * 4;
    uint2 u = *(const uint2*)p;
    const bf16* pb = (const bf16*)&u;
    return (f32x4){bf2f(pb[0]), bf2f(pb[1]), bf2f(pb[2]), bf2f(pb[3])};
  };

#pragma unroll
  for (int dwi = 0; dwi < 3; ++dwi) {
    win[0][dwi] = ld4(0, dwi);
    win[1][dwi] = ld4(1, dwi);
  }
#pragma unroll
  for (int orow = 0; orow < 16; ++orow) {
    int rnew = orow + 2;
    int ringn = rnew % 3;
#pragma unroll
    for (int dwi = 0; dwi < 3; ++dwi) win[ringn][dwi] = ld4(rnew, dwi);
    f32x4 acc = (f32x4){0.f, 0.f, 0.f, 0.f};
#pragma unroll
    for (int dr = 0; dr < 3; ++dr) {
      int ring = (orow + dr) % 3;
#pragma unroll
      for (int dwi = 0; dwi < 3; ++dwi) {
#pragma unroll
        for (int j = 0; j < 4; ++j)
          acc[j] = fmaf(win[ring][dwi][j], wv[dr * 3 + dwi][j], acc[j]);
      }
    }
#pragma unroll
    for (int j = 0; j < 4; ++j) { acc_s += acc[j]; acc_ss += acc[j] * acc[j]; }
    if (!(orow & 1) && !(w & 1)) {
      int hglob = h0 + orow;
      int pos2 = (hglob >> 1) * 32 + (w >> 1);
      bf16 tmp[4];
#pragma unroll
      for (int j = 0; j < 4; ++j) tmp[j] = f2bf(acc[j]);
      *(uint2*)((char*)h2cl + ((size_t)(b * 1024 + pos2) * 512 + hc0 + q * 4) * 2) =
          *(const uint2*)tmp;
    }
  }

  // ---- stats reduction: one atomic pair per block into (b, hcb) ----
#pragma unroll
  for (int off = 32; off; off >>= 1) {
    acc_s += __shfl_down(acc_s, off, 64);
    acc_ss += __shfl_down(acc_ss, off, 64);
  }
  int wave = t >> 6;
  if ((t & 63) == 0) { red2[wave][0] = acc_s; red2[wave][1] = acc_ss; }
  __syncthreads();
  if (t < 2) {
    float v = red2[0][t] + red2[1][t] + red2[2][t] + red2[3][t];
    atomicAdd(&stats2[(b * 8 + hcb) * 2 + t], v);
  }
}

// ---------------- pw2 MFMA v2 (GN2+SiLU fused; grid 512, co-halved) --------
// h3[co=128][n=16384] = w[co][hc] @ silu(GN2(h2raw))[n][hc]
// blk = mhalf(2) x nblk(256): block computes co [mhalf*64, +64) x n [nblk*64, +64)
__global__ __launch_bounds__(256) void pw2_mfma(
    const bf16* __restrict__ h2, const bf16* __restrict__ wp2T,
    const float* __restrict__ st2, const float* __restrict__ gs2,
    const float* __restrict__ gb2, float* __restrict__ h3,
    float* __restrict__ stats3) {
  __shared__ __align__(16) char als[2][4096];
  __shared__ __align__(16) char bls[2][4096];
  __shared__ float red[4][4][2];
  int blk = blockIdx.x;
  int mhalf = blk >> 8;            // 0..1
  int nblk = blk & 255;
  int n0 = nblk * 64;
  int m0 = mhalf * 64;
  int b = n0 >> 10, posb = n0 & 1023;
  int t = threadIdx.x, lane = t & 63, wave = t >> 6;
  int quad = lane >> 4, l15 = lane & 15;
  int wbase = wave * 16;
  int c4 = t >> 6, r = t & 63;

  // normalize+silu h2 octet (kc,c4) for row n0+r, write 16B to dst
  auto load_bls = [&](char* dst, int kc) {
    int hc0 = (kc * 4 + c4) * 8;
    int g = hc0 >> 6;
    float S = st2[(b * 8 + g) * 2], SS = st2[(b * 8 + g) * 2 + 1];
    float mean = S * (1.f / 262144.f);
    float rstd = rsqrtf(SS * (1.f / 262144.f) - mean * mean + 1e-5f);
    uint4 u = *(const uint4*)((const char*)h2 + (size_t)(n0 + r) * 1024 +
                              (size_t)(kc * 4 + c4) * 16);
    const bf16* pv = (const bf16*)&u;
    bf16 outv[8];
#pragma unroll
    for (int j = 0; j < 8; ++j) {
      float xv = bf2f(pv[j]);
      xv = (xv - mean) * rstd * gs2[hc0 + j] + gb2[hc0 + j];
      outv[j] = f2bf(siluf(xv));
    }
    *(uint4*)dst = *(const uint4*)outv;
  };
  // stage A half-tile: 64 co rows for this kc
  auto load_als = [&](char* dstbase, int kc) {
    *(uint4*)(dstbase + c4 * 1024 + r * 16) =
        *(const uint4*)((const char*)wp2T + (size_t)(m0 + r) * 1024 +
                        (size_t)(kc * 4 + c4) * 16);
  };

  f32x4 acc[4];
#pragma unroll
  for (int mt = 0; mt < 4; ++mt) acc[mt] = (f32x4){0.f, 0.f, 0.f, 0.f};

  {
    load_als(als[0], 0);
    load_bls(bls[0] + c4 * 1024 + r * 16, 0);
  }
#pragma unroll
  for (int kc = 0; kc < 16; ++kc) {
    __syncthreads();
    if (kc + 1 < 16) {
      int nb = (kc + 1) & 1;
      load_als(als[nb], kc + 1);
      load_bls(bls[nb] + c4 * 1024 + r * 16, kc + 1);
    }
    int buf = kc & 1;
    bf16x8 bf1 = *(const bf16x8*)(bls[buf] + quad * 1024 + (wbase + l15) * 16);
#pragma unroll
    for (int mt = 0; mt < 4; ++mt) {
      bf16x8 af = *(const bf16x8*)(als[buf] + quad * 1024 + (mt * 16 + l15) * 16);
      acc[mt] = __builtin_amdgcn_mfma_f32_16x16x32_bf16(af, bf1, acc[mt], 0, 0, 0);
    }
  }

#pragma unroll
  for (int mt = 0; mt < 4; ++mt) {
    float s = 0.f, ss = 0.f;
    int pos = posb + wbase + l15;
#pragma unroll
    for (int rr = 0; rr < 4; ++rr) {
      float v = acc[mt][rr];
      s += v;
      ss += v * v;
      int co = m0 + mt * 16 + quad * 4 + rr;
      h3[(size_t)(b * 128 + co) * 1024 + pos] = v;
    }
#pragma unroll
    for (int off = 32; off; off >>= 1) {
      s += __shfl_down(s, off, 64);
      ss += __shfl_down(ss, off, 64);
    }
    if (lane == 0) { red[wave][mt][0] = s; red[wave][mt][1] = ss; }
  }
  __syncthreads();
  if (t < 8) {
    int mt = t >> 1, which = t & 1;
    float v = red[0][mt][which] + red[1][mt][which] + red[2][mt][which] + red[3][mt][which];
    atomicAdd(&stats3[(b * 8 + mhalf * 4 + mt) * 2 + which], v);
  }
}

// ---------------- final GN+SiLU -> d_out (fp32, float4) --------------------
__global__ void out_kernel(const float* __restrict__ h3, const float* __restrict__ stats,
                           const float* __restrict__ gs, const float* __restrict__ gb,
                           float* __restrict__ out) {
  const int total4 = (B_ * COUT_ * 1024) >> 2;
  for (int i4 = blockIdx.x * blockDim.x + threadIdx.x; i4 < total4;
       i4 += gridDim.x * blockDim.x) {
    int idx = i4 << 2;
    int c = (idx >> 10) & 127;     // uniform over the 4 elements (1024%4==0)
    int b = idx >> 17;
    int bg = b * 8 + (c >> 4);
    float S = stats[bg * 2], SS = stats[bg * 2 + 1];
    float mean = S * (1.f / 16384.f);
    float var = SS * (1.f / 16384.f) - mean * mean;
    float rstd = rsqrtf(var + 1e-5f);
    float sc = rstd * gs[c];
    float sh = gb[c] - mean * sc;
    float4 hv = *(const float4*)(h3 + idx);
    float4 res;
    res.x = siluf(hv.x * sc + sh);
    res.y = siluf(hv.y * sc + sh);
    res.z = siluf(hv.z * sc + sh);
    res.w = siluf(hv.w * sc + sh);
    *(float4*)(out + idx) = res;
  }
}

extern "C" void kernel_launch(void* const* d_in, const int* in_sizes, int n_in,
                              void* d_out, int out_size, void* d_ws, size_t ws_size,
                              hipStream_t stream) {
  const float* x = (const float*)d_in[0];
  const float* w_exp = (const float*)d_in[1];
  const float* gn_exp_s = (const float*)d_in[2];
  const float* gn_exp_b = (const float*)d_in[3];
  const float* w1 = (const float*)d_in[4];
  const float* b1 = (const float*)d_in[5];
  const float* w2 = (const float*)d_in[6];
  const float* b2 = (const float*)d_in[7];
  const float* w_pw1 = (const float*)d_in[8];
  const float* gn1_s = (const float*)d_in[9];
  const float* gn1_b = (const float*)d_in[10];
  const float* w_dw = (const float*)d_in[11];
  const float* gn2_s = (const float*)d_in[12];
  const float* gn2_b = (const float*)d_in[13];
  const float* w_pw2 = (const float*)d_in[14];
  const float* gn3_s = (const float*)d_in[15];
  const float* gn3_b = (const float*)d_in[16];

  char* ws = (char*)d_ws;
  const size_t WP1T_OFF = 16384;
  const size_t WP2T_OFF = WP1T_OFF + 131072;
  const size_t XT_OFF = WP2T_OFF + 131072;                 // 278528
  const size_t WT_OFF = XT_OFF + 16777216;                 // 17055744
  const size_t YS_OFF = WT_OFF + 2359296;                  // 19415040
  const size_t NEEDED = YS_OFF + 134217728;                // 153632768
  if (ws_size < NEEDED) return;

  float* wts = (float*)ws;
  float* stats1 = (float*)(ws + 1024);
  float* stats2 = (float*)(ws + 2048);
  float* stats3 = (float*)(ws + 3072);
  float* statsE = (float*)(ws + 4096);
  bf16* wp1T = (bf16*)(ws + WP1T_OFF);
  bf16* wp2T = (bf16*)(ws + WP2T_OFF);
  bf16* xT = (bf16*)(ws + XT_OFF);
  bf16* ccl = (bf16*)(ws + XT_OFF);
  bf16* wT = (bf16*)(ws + WT_OFF);
  bf16* ys = (bf16*)(ws + YS_OFF);
  bf16* h1cl = (bf16*)(ws + YS_OFF);
  bf16* h2cl = (bf16*)(ws + YS_OFF + 67108864);
  float* h3 = (float*)(ws + YS_OFF + 83886080);

  prep_kernel<<<6145, 256, 0, stream>>>(x, xT, w_exp, wT, w_pw1, w_pw2, wp1T, wp2T,
                                        w1, b1, w2, b2, wts);
  conv_mfma<<<1024, 256, 0, stream>>>(xT, wT, statsE, ys, 0);
  conv_mfma<<<1024, 256, 0, stream>>>(xT, wT, statsE, ys, 4);
  combine_cl<<<B_ * 64, 256, 0, stream>>>(x, ys, statsE, gn_exp_s, gn_exp_b, wts, ccl);
  pw1_mfma<<<512, 256, 0, stream>>>(ccl, wp1T, h1cl, stats1);
  dw_cl<<<B_ * 32 * 4, 256, 0, stream>>>(h1cl, w_dw, stats1, gn1_s, gn1_b, h2cl, stats2);
  pw2_mfma<<<512, 256, 0, stream>>>(h2cl, wp2T, stats2, gn2_s, gn2_b, h3, stats3);
  out_kernel<<<1024, 256, 0, stream>>>(h3, stats3, gn3_s, gn3_b, (float*)d_out);
}